// Round 1
// baseline (7554.622 us; speedup 1.0000x reference)
//
#include <hip/hip_runtime.h>

typedef long long i64;

#define NU 100000
#define NP 100000

// ---------------- scatter kernels (atomic baseline) ----------------
// 32 lanes per edge, float4 per lane over 128 features.
__global__ __launch_bounds__(256) void k_scatter128(
    const float* __restrict__ feat, const int* __restrict__ esrc,
    const int* __restrict__ edst, int nedge,
    float* __restrict__ acc, float* __restrict__ cnt)
{
    int t = blockIdx.x * 256 + threadIdx.x;
    int e = t >> 5;
    if (e >= nedge) return;
    int lane = t & 31;
    int s = esrc[e], d = edst[e];
    float g[4];
    *(float4*)g = *(const float4*)(feat + (i64)s * 128 + lane * 4);
    float* a = acc + (i64)d * 128 + lane * 4;
    atomicAdd(a + 0, g[0]); atomicAdd(a + 1, g[1]);
    atomicAdd(a + 2, g[2]); atomicAdd(a + 3, g[3]);
    if (lane == 0) atomicAdd(cnt + d, 1.0f);
}

__global__ __launch_bounds__(256) void k_scatter_com(
    const float* __restrict__ hu, const float* __restrict__ ec,
    const int* __restrict__ esrc, const int* __restrict__ edst, int nedge,
    float* __restrict__ accU, float* __restrict__ accE, float* __restrict__ cnt)
{
    int t = blockIdx.x * 256 + threadIdx.x;
    int e = t >> 5;
    if (e >= nedge) return;
    int lane = t & 31;
    int s = esrc[e], d = edst[e];
    float g[4];
    *(float4*)g = *(const float4*)(hu + (i64)s * 128 + lane * 4);
    float* a = accU + (i64)d * 128 + lane * 4;
    atomicAdd(a + 0, g[0]); atomicAdd(a + 1, g[1]);
    atomicAdd(a + 2, g[2]); atomicAdd(a + 3, g[3]);
    if (lane < 16) {
        float h[4];
        *(float4*)h = *(const float4*)(ec + (i64)e * 64 + lane * 4);
        float* a2 = accE + (i64)d * 64 + lane * 4;
        atomicAdd(a2 + 0, h[0]); atomicAdd(a2 + 1, h[1]);
        atomicAdd(a2 + 2, h[2]); atomicAdd(a2 + 3, h[3]);
    }
    if (lane == 0) atomicAdd(cnt + d, 1.0f);
}

// ---------------- rowwise GEMM: out[u] = sfin*( segratio*X0@W0 + X1@W1 )/c + bias ----
// thread tile: 4 users x 4 features. 32 users per 256-thread block.
__device__ __forceinline__ void seg_accum(const float* __restrict__ X, int K,
        const float* __restrict__ W, int u0, int fg, float acc[4][4])
{
    const float* xr0 = X + (i64)(u0 + 0) * K;
    const float* xr1 = X + (i64)(u0 + 1) * K;
    const float* xr2 = X + (i64)(u0 + 2) * K;
    const float* xr3 = X + (i64)(u0 + 3) * K;
    for (int k = 0; k < K; k += 4) {
        float xa[4], xb[4], xc[4], xd[4];
        *(float4*)xa = *(const float4*)(xr0 + k);
        *(float4*)xb = *(const float4*)(xr1 + k);
        *(float4*)xc = *(const float4*)(xr2 + k);
        *(float4*)xd = *(const float4*)(xr3 + k);
#pragma unroll
        for (int j = 0; j < 4; ++j) {
            float w[4];
            *(float4*)w = *(const float4*)(W + (i64)(k + j) * 128 + fg * 4);
#pragma unroll
            for (int q = 0; q < 4; ++q) {
                acc[0][q] = fmaf(xa[j], w[q], acc[0][q]);
                acc[1][q] = fmaf(xb[j], w[q], acc[1][q]);
                acc[2][q] = fmaf(xc[j], w[q], acc[2][q]);
                acc[3][q] = fmaf(xd[j], w[q], acc[3][q]);
            }
        }
    }
}

__global__ __launch_bounds__(256) void k_rowgemm(
    const float* __restrict__ X0, int K0, const float* __restrict__ W0,
    const float* __restrict__ X1, int K1, const float* __restrict__ W1,
    float segratio, float sfin,
    const float* __restrict__ b0, float bs0,
    const float* __restrict__ b1, float bs1,
    const float* __restrict__ cnt, float* __restrict__ out)
{
    const int fg = threadIdx.x & 31;
    const int ug = threadIdx.x >> 5;
    const int u0 = blockIdx.x * 32 + ug * 4;

    float acc[4][4];
#pragma unroll
    for (int i = 0; i < 4; ++i)
#pragma unroll
        for (int q = 0; q < 4; ++q) acc[i][q] = 0.f;

    seg_accum(X0, K0, W0, u0, fg, acc);
    if (K1 > 0) {
        if (segratio != 1.0f) {
#pragma unroll
            for (int i = 0; i < 4; ++i)
#pragma unroll
                for (int q = 0; q < 4; ++q) acc[i][q] *= segratio;
        }
        seg_accum(X1, K1, W1, u0, fg, acc);
    }

    float bv[4] = {0.f, 0.f, 0.f, 0.f};
    if (b0) {
        float tb[4]; *(float4*)tb = *(const float4*)(b0 + fg * 4);
#pragma unroll
        for (int q = 0; q < 4; ++q) bv[q] = fmaf(bs0, tb[q], bv[q]);
    }
    if (b1) {
        float tb[4]; *(float4*)tb = *(const float4*)(b1 + fg * 4);
#pragma unroll
        for (int q = 0; q < 4; ++q) bv[q] = fmaf(bs1, tb[q], bv[q]);
    }

#pragma unroll
    for (int i = 0; i < 4; ++i) {
        float o[4];
        if (cnt) {
            float c = cnt[u0 + i];
            if (c > 0.f) {
                float m = sfin / c;
#pragma unroll
                for (int q = 0; q < 4; ++q) o[q] = fmaf(acc[i][q], m, bv[q]);
            } else {
#pragma unroll
                for (int q = 0; q < 4; ++q) o[q] = 0.f;
            }
        } else {
#pragma unroll
            for (int q = 0; q < 4; ++q) o[q] = fmaf(acc[i][q], sfin, bv[q]);
        }
        *(float4*)(out + (i64)(u0 + i) * 128 + fg * 4) = *(float4*)o;
    }
}

// ---------------- LayerNorm + ReLU over 128-dim rows, in place ----------------
__global__ __launch_bounds__(256) void k_ln_relu(
    float* __restrict__ z, const float* __restrict__ g, const float* __restrict__ b)
{
    int t = blockIdx.x * 256 + threadIdx.x;
    int u = t >> 5;
    if (u >= NU) return;
    int lane = t & 31;
    float x[4];
    *(float4*)x = *(const float4*)(z + (i64)u * 128 + lane * 4);
    float s = x[0] + x[1] + x[2] + x[3];
#pragma unroll
    for (int m = 1; m < 32; m <<= 1) s += __shfl_xor(s, m, 32);
    float mu = s * (1.f / 128.f);
    float d0 = x[0] - mu, d1 = x[1] - mu, d2 = x[2] - mu, d3 = x[3] - mu;
    float sq = d0 * d0 + d1 * d1 + d2 * d2 + d3 * d3;
#pragma unroll
    for (int m = 1; m < 32; m <<= 1) sq += __shfl_xor(sq, m, 32);
    float rs = rsqrtf(sq * (1.f / 128.f) + 1e-5f);
    float gg[4], bb[4];
    *(float4*)gg = *(const float4*)(g + lane * 4);
    *(float4*)bb = *(const float4*)(b + lane * 4);
    float o[4];
    o[0] = fmaxf(0.f, d0 * rs * gg[0] + bb[0]);
    o[1] = fmaxf(0.f, d1 * rs * gg[1] + bb[1]);
    o[2] = fmaxf(0.f, d2 * rs * gg[2] + bb[2]);
    o[3] = fmaxf(0.f, d3 * rs * gg[3] + bb[3]);
    *(float4*)(z + (i64)u * 128 + lane * 4) = *(float4*)o;
}

// ---------------- divide accumulated plane by count (user_new) ----------------
__global__ __launch_bounds__(256) void k_meandiv(
    float* __restrict__ acc, const float* __restrict__ cnt)
{
    int t = blockIdx.x * 256 + threadIdx.x;
    int u = t >> 5;
    if (u >= NU) return;
    int lane = t & 31;
    float c = cnt[u];
    float m = c > 0.f ? 1.f / c : 0.f;
    float v[4];
    *(float4*)v = *(const float4*)(acc + (i64)u * 128 + lane * 4);
    v[0] *= m; v[1] *= m; v[2] *= m; v[3] *= m;
    *(float4*)(acc + (i64)u * 128 + lane * 4) = *(float4*)v;
}

extern "C" void kernel_launch(void* const* d_in, const int* in_sizes, int n_in,
                              void* d_out, int out_size, void* d_ws, size_t ws_size,
                              hipStream_t stream)
{
    const float* h_user   = (const float*)d_in[0];
    // d_in[1] = h_post: unused by the reference
    const float* user_ctx = (const float*)d_in[2];
    const float* e_com    = (const float*)d_in[3];
    const int* pub_src = (const int*)d_in[4];
    const int* pub_dst = (const int*)d_in[5];
    const int* com_src = (const int*)d_in[6];
    const int* com_dst = (const int*)d_in[7];
    const int* ucu_src = (const int*)d_in[8];
    const int* ucu_dst = (const int*)d_in[9];
    const float* W_pub  = (const float*)d_in[10];
    const float* b_pub  = (const float*)d_in[11];
    const float* W_com  = (const float*)d_in[12];
    const float* b_com  = (const float*)d_in[13];
    const float* W_conv = (const float*)d_in[14];
    const float* b_conv = (const float*)d_in[15];
    const float* ln_g   = (const float*)d_in[16];
    const float* ln_b   = (const float*)d_in[17];
    const float* W_ecom = (const float*)d_in[18];
    const float* b_ecom = (const float*)d_in[19];

    const int n_pub = in_sizes[4];
    const int n_com = in_sizes[6];
    const int n_ucu = in_sizes[8];

    float* out0 = (float*)d_out;              // acc_pub  -> post_pub
    float* out1 = out0 + (i64)NP * 128;       // acc_comU -> post_com
    float* out2 = out1 + (i64)NP * 128;       // acc_ucu  -> user_new

    char* ws = (char*)d_ws;
    float* zbuf = (float*)ws;                                   // NU*128
    float* accE = (float*)(ws + (i64)NU * 128 * 4);             // NP*64
    float* cntP = (float*)(ws + (i64)NU * 128 * 4 + (i64)NP * 64 * 4);
    float* cntC = cntP + NP;
    float* cntU = cntC + NP;

    // zero output planes (used as accumulators) + accE + counts
    hipMemsetAsync(d_out, 0, (i64)3 * NP * 128 * 4, stream);
    hipMemsetAsync(accE, 0, (i64)NP * 64 * 4 + (i64)(2 * NP + NU) * 4, stream);

    // z = LN(concat(h_user, user_ctx) @ W_conv + b_conv) -> relu
    k_rowgemm<<<NU / 32, 256, 0, stream>>>(
        h_user, 128, W_conv, user_ctx, 64, W_conv + 128 * 128,
        1.f, 1.f, b_conv, 1.f, nullptr, 0.f, nullptr, zbuf);
    k_ln_relu<<<NU * 32 / 256, 256, 0, stream>>>(zbuf, ln_g, ln_b);

    // edge scatters (atomic accumulate raw features + counts)
    k_scatter128<<<(n_pub * 32 + 255) / 256, 256, 0, stream>>>(
        h_user, pub_src, pub_dst, n_pub, out0, cntP);
    k_scatter_com<<<(int)(((i64)n_com * 32 + 255) / 256), 256, 0, stream>>>(
        h_user, e_com, com_src, com_dst, n_com, out1, accE, cntC);
    k_scatter128<<<(int)(((i64)n_ucu * 32 + 255) / 256), 256, 0, stream>>>(
        zbuf, ucu_src, ucu_dst, n_ucu, out2, cntU);

    // post_pub = (acc_pub @ W_pub)/c + b_pub   (0 if c==0), in place
    k_rowgemm<<<NP / 32, 256, 0, stream>>>(
        out0, 128, W_pub, nullptr, 0, nullptr,
        1.f, 1.f, b_pub, 1.f, nullptr, 0.f, cntP, out0);

    // post_com = (0.7*accU@W_com + 0.3*accE@W_ecom)/c + 0.7*b_com + 0.3*b_ecom
    k_rowgemm<<<NP / 32, 256, 0, stream>>>(
        out1, 128, W_com, accE, 64, W_ecom,
        0.7f / 0.3f, 0.3f, b_com, 0.7f, b_ecom, 0.3f, cntC, out1);

    // user_new = acc_ucu / c
    k_meandiv<<<NU * 32 / 256, 256, 0, stream>>>(out2, cntU);
}

// Round 2
// 1232.841 us; speedup vs baseline: 6.1278x; 6.1278x over previous
//
#include <hip/hip_runtime.h>

typedef long long i64;

#define NU 100000
#define NP 100000
#define NSEG 300000   // pub counts [0,NP), com counts [NP,2NP), ucu counts [2NP,2NP+NU)

// ---------------- CSR build ----------------
__global__ __launch_bounds__(256) void k_hist(
    const int* __restrict__ dst, int n, int* __restrict__ cnt)
{
    int e = blockIdx.x * 256 + threadIdx.x;
    if (e < n) atomicAdd(cnt + dst[e], 1);
}

__global__ __launch_bounds__(1024) void k_scan_block(
    const int* __restrict__ in, int n, int* __restrict__ out, int* __restrict__ bsum)
{
    __shared__ int sm[1024];
    int gid = blockIdx.x * 1024 + threadIdx.x;
    int v = (gid < n) ? in[gid] : 0;
    sm[threadIdx.x] = v;
    __syncthreads();
    for (int off = 1; off < 1024; off <<= 1) {
        int t = (threadIdx.x >= (unsigned)off) ? sm[threadIdx.x - off] : 0;
        __syncthreads();
        sm[threadIdx.x] += t;
        __syncthreads();
    }
    if (gid < n) out[gid] = sm[threadIdx.x] - v;      // exclusive
    if (threadIdx.x == 1023) bsum[blockIdx.x] = sm[1023];
}

__global__ __launch_bounds__(512) void k_scan_bsum(int* __restrict__ bsum, int nb)
{
    __shared__ int sm[512];
    int v = (threadIdx.x < (unsigned)nb) ? bsum[threadIdx.x] : 0;
    sm[threadIdx.x] = v;
    __syncthreads();
    for (int off = 1; off < 512; off <<= 1) {
        int t = (threadIdx.x >= (unsigned)off) ? sm[threadIdx.x - off] : 0;
        __syncthreads();
        sm[threadIdx.x] += t;
        __syncthreads();
    }
    if (threadIdx.x < (unsigned)nb) bsum[threadIdx.x] = sm[threadIdx.x] - v;  // exclusive
}

__global__ __launch_bounds__(1024) void k_scan_add(
    int* __restrict__ rptr, int n, const int* __restrict__ bsum,
    int* __restrict__ cursor, int total)
{
    int gid = blockIdx.x * 1024 + threadIdx.x;
    if (gid < n) {
        int v = rptr[gid] + bsum[blockIdx.x];
        rptr[gid] = v;
        cursor[gid] = v;
    }
    if (gid == 0) rptr[n] = total;
}

__global__ __launch_bounds__(256) void k_fill(
    const int* __restrict__ src, const int* __restrict__ dst, int n,
    int* __restrict__ cursor, int* __restrict__ esrc,
    int* __restrict__ eid, int ebase)
{
    int e = blockIdx.x * 256 + threadIdx.x;
    if (e >= n) return;
    int d = dst[e];
    int pos = atomicAdd(cursor + d, 1);
    esrc[pos] = src[e];
    if (eid) eid[pos - ebase] = e;
}

// ---------------- CSR gathers: one 64-lane wave per dst row ----------------
__global__ __launch_bounds__(256) void k_gather128(
    const float* __restrict__ feat, const int* __restrict__ rp,
    const int* __restrict__ esrc, int nrow, float* __restrict__ out, int divide)
{
    int t = blockIdx.x * 256 + threadIdx.x;
    int row = t >> 6;
    if (row >= nrow) return;
    int lane = t & 63;
    int beg = rp[row], end = rp[row + 1];
    float ax = 0.f, ay = 0.f;
    int j = beg;
    for (; j + 1 < end; j += 2) {
        int s0 = esrc[j], s1 = esrc[j + 1];
        float2 a = *(const float2*)(feat + (i64)s0 * 128 + lane * 2);
        float2 b = *(const float2*)(feat + (i64)s1 * 128 + lane * 2);
        ax += a.x + b.x; ay += a.y + b.y;
    }
    if (j < end) {
        int s = esrc[j];
        float2 a = *(const float2*)(feat + (i64)s * 128 + lane * 2);
        ax += a.x; ay += a.y;
    }
    if (divide) {
        int deg = end - beg;
        float m = deg > 0 ? 1.f / (float)deg : 0.f;
        ax *= m; ay *= m;
    }
    float2 o; o.x = ax; o.y = ay;
    *(float2*)(out + (i64)row * 128 + lane * 2) = o;
}

__global__ __launch_bounds__(256) void k_gather_com(
    const float* __restrict__ hu, const float* __restrict__ ec,
    const int* __restrict__ rp, const int* __restrict__ esrc,
    const int* __restrict__ eid, int ebase, int nrow,
    float* __restrict__ outU, float* __restrict__ outE)
{
    int t = blockIdx.x * 256 + threadIdx.x;
    int row = t >> 6;
    if (row >= nrow) return;
    int lane = t & 63;
    int beg = rp[row], end = rp[row + 1];
    float ax = 0.f, ay = 0.f, aE = 0.f;
    int j = beg;
    for (; j + 1 < end; j += 2) {
        int s0 = esrc[j], s1 = esrc[j + 1];
        int e0 = eid[j - ebase], e1 = eid[j + 1 - ebase];
        float2 a = *(const float2*)(hu + (i64)s0 * 128 + lane * 2);
        float2 b = *(const float2*)(hu + (i64)s1 * 128 + lane * 2);
        float ea = ec[(i64)e0 * 64 + lane];
        float eb = ec[(i64)e1 * 64 + lane];
        ax += a.x + b.x; ay += a.y + b.y; aE += ea + eb;
    }
    if (j < end) {
        int s = esrc[j];
        int e0 = eid[j - ebase];
        float2 a = *(const float2*)(hu + (i64)s * 128 + lane * 2);
        ax += a.x; ay += a.y; aE += ec[(i64)e0 * 64 + lane];
    }
    float2 o; o.x = ax; o.y = ay;
    *(float2*)(outU + (i64)row * 128 + lane * 2) = o;
    outE[(i64)row * 64 + lane] = aE;
}

// ---------------- rowwise GEMM: out[u] = sfin*( segratio*X0@W0 + X1@W1 )/deg + bias ----
__device__ __forceinline__ void seg_accum(const float* __restrict__ X, int K,
        const float* __restrict__ W, int u0, int fg, float acc[4][4])
{
    const float* xr0 = X + (i64)(u0 + 0) * K;
    const float* xr1 = X + (i64)(u0 + 1) * K;
    const float* xr2 = X + (i64)(u0 + 2) * K;
    const float* xr3 = X + (i64)(u0 + 3) * K;
    for (int k = 0; k < K; k += 4) {
        float xa[4], xb[4], xc[4], xd[4];
        *(float4*)xa = *(const float4*)(xr0 + k);
        *(float4*)xb = *(const float4*)(xr1 + k);
        *(float4*)xc = *(const float4*)(xr2 + k);
        *(float4*)xd = *(const float4*)(xr3 + k);
#pragma unroll
        for (int j = 0; j < 4; ++j) {
            float w[4];
            *(float4*)w = *(const float4*)(W + (i64)(k + j) * 128 + fg * 4);
#pragma unroll
            for (int q = 0; q < 4; ++q) {
                acc[0][q] = fmaf(xa[j], w[q], acc[0][q]);
                acc[1][q] = fmaf(xb[j], w[q], acc[1][q]);
                acc[2][q] = fmaf(xc[j], w[q], acc[2][q]);
                acc[3][q] = fmaf(xd[j], w[q], acc[3][q]);
            }
        }
    }
}

__global__ __launch_bounds__(256) void k_rowgemm(
    const float* __restrict__ X0, int K0, const float* __restrict__ W0,
    const float* __restrict__ X1, int K1, const float* __restrict__ W1,
    float segratio, float sfin,
    const float* __restrict__ b0, float bs0,
    const float* __restrict__ b1, float bs1,
    const int* __restrict__ rp, float* __restrict__ out)
{
    const int fg = threadIdx.x & 31;
    const int ug = threadIdx.x >> 5;
    const int u0 = blockIdx.x * 32 + ug * 4;

    float acc[4][4];
#pragma unroll
    for (int i = 0; i < 4; ++i)
#pragma unroll
        for (int q = 0; q < 4; ++q) acc[i][q] = 0.f;

    seg_accum(X0, K0, W0, u0, fg, acc);
    if (K1 > 0) {
        if (segratio != 1.0f) {
#pragma unroll
            for (int i = 0; i < 4; ++i)
#pragma unroll
                for (int q = 0; q < 4; ++q) acc[i][q] *= segratio;
        }
        seg_accum(X1, K1, W1, u0, fg, acc);
    }

    float bv[4] = {0.f, 0.f, 0.f, 0.f};
    if (b0) {
        float tb[4]; *(float4*)tb = *(const float4*)(b0 + fg * 4);
#pragma unroll
        for (int q = 0; q < 4; ++q) bv[q] = fmaf(bs0, tb[q], bv[q]);
    }
    if (b1) {
        float tb[4]; *(float4*)tb = *(const float4*)(b1 + fg * 4);
#pragma unroll
        for (int q = 0; q < 4; ++q) bv[q] = fmaf(bs1, tb[q], bv[q]);
    }

#pragma unroll
    for (int i = 0; i < 4; ++i) {
        float o[4];
        if (rp) {
            int deg = rp[u0 + i + 1] - rp[u0 + i];
            if (deg > 0) {
                float m = sfin / (float)deg;
#pragma unroll
                for (int q = 0; q < 4; ++q) o[q] = fmaf(acc[i][q], m, bv[q]);
            } else {
#pragma unroll
                for (int q = 0; q < 4; ++q) o[q] = 0.f;
            }
        } else {
#pragma unroll
            for (int q = 0; q < 4; ++q) o[q] = fmaf(acc[i][q], sfin, bv[q]);
        }
        *(float4*)(out + (i64)(u0 + i) * 128 + fg * 4) = *(float4*)o;
    }
}

// ---------------- LayerNorm + ReLU over 128-dim rows, in place ----------------
__global__ __launch_bounds__(256) void k_ln_relu(
    float* __restrict__ z, const float* __restrict__ g, const float* __restrict__ b)
{
    int t = blockIdx.x * 256 + threadIdx.x;
    int u = t >> 5;
    if (u >= NU) return;
    int lane = t & 31;
    float x[4];
    *(float4*)x = *(const float4*)(z + (i64)u * 128 + lane * 4);
    float s = x[0] + x[1] + x[2] + x[3];
#pragma unroll
    for (int m = 1; m < 32; m <<= 1) s += __shfl_xor(s, m, 32);
    float mu = s * (1.f / 128.f);
    float d0 = x[0] - mu, d1 = x[1] - mu, d2 = x[2] - mu, d3 = x[3] - mu;
    float sq = d0 * d0 + d1 * d1 + d2 * d2 + d3 * d3;
#pragma unroll
    for (int m = 1; m < 32; m <<= 1) sq += __shfl_xor(sq, m, 32);
    float rs = rsqrtf(sq * (1.f / 128.f) + 1e-5f);
    float gg[4], bb[4];
    *(float4*)gg = *(const float4*)(g + lane * 4);
    *(float4*)bb = *(const float4*)(b + lane * 4);
    float o[4];
    o[0] = fmaxf(0.f, d0 * rs * gg[0] + bb[0]);
    o[1] = fmaxf(0.f, d1 * rs * gg[1] + bb[1]);
    o[2] = fmaxf(0.f, d2 * rs * gg[2] + bb[2]);
    o[3] = fmaxf(0.f, d3 * rs * gg[3] + bb[3]);
    *(float4*)(z + (i64)u * 128 + lane * 4) = *(float4*)o;
}

extern "C" void kernel_launch(void* const* d_in, const int* in_sizes, int n_in,
                              void* d_out, int out_size, void* d_ws, size_t ws_size,
                              hipStream_t stream)
{
    const float* h_user   = (const float*)d_in[0];
    const float* user_ctx = (const float*)d_in[2];
    const float* e_com    = (const float*)d_in[3];
    const int* pub_src = (const int*)d_in[4];
    const int* pub_dst = (const int*)d_in[5];
    const int* com_src = (const int*)d_in[6];
    const int* com_dst = (const int*)d_in[7];
    const int* ucu_src = (const int*)d_in[8];
    const int* ucu_dst = (const int*)d_in[9];
    const float* W_pub  = (const float*)d_in[10];
    const float* b_pub  = (const float*)d_in[11];
    const float* W_com  = (const float*)d_in[12];
    const float* b_com  = (const float*)d_in[13];
    const float* W_conv = (const float*)d_in[14];
    const float* b_conv = (const float*)d_in[15];
    const float* ln_g   = (const float*)d_in[16];
    const float* ln_b   = (const float*)d_in[17];
    const float* W_ecom = (const float*)d_in[18];
    const float* b_ecom = (const float*)d_in[19];

    const int n_pub = in_sizes[4];
    const int n_com = in_sizes[6];
    const int n_ucu = in_sizes[8];
    const int total = n_pub + n_com + n_ucu;

    float* out0 = (float*)d_out;              // sum_pub  -> post_pub (in-place gemm)
    float* out1 = out0 + (i64)NP * 128;       // sum_comU -> post_com (in-place gemm)
    float* out2 = out1 + (i64)NP * 128;       // user_new (written final by gather)

    char* ws = (char*)d_ws;
    float* zbuf = (float*)ws;                                 // NU*128 f32
    float* accE = zbuf + (i64)NU * 128;                       // NP*64 f32
    int* cnt    = (int*)(accE + (i64)NP * 64);                // NSEG
    int* rptr   = cnt + NSEG;                                 // NSEG+1
    int* cursor = rptr + NSEG + 1;                            // NSEG
    int* bsum   = cursor + NSEG;                              // 512
    int* esrc   = bsum + 512;                                 // total
    int* eidC   = esrc + total;                               // n_com

    const int NB = (NSEG + 1023) / 1024;   // 293 scan blocks

    // ---- CSR build ----
    hipMemsetAsync(cnt, 0, (size_t)NSEG * 4, stream);
    k_hist<<<(n_pub + 255) / 256, 256, 0, stream>>>(pub_dst, n_pub, cnt);
    k_hist<<<(n_com + 255) / 256, 256, 0, stream>>>(com_dst, n_com, cnt + NP);
    k_hist<<<(n_ucu + 255) / 256, 256, 0, stream>>>(ucu_dst, n_ucu, cnt + 2 * NP);
    k_scan_block<<<NB, 1024, 0, stream>>>(cnt, NSEG, rptr, bsum);
    k_scan_bsum<<<1, 512, 0, stream>>>(bsum, NB);
    k_scan_add<<<NB, 1024, 0, stream>>>(rptr, NSEG, bsum, cursor, total);
    k_fill<<<(n_pub + 255) / 256, 256, 0, stream>>>(
        pub_src, pub_dst, n_pub, cursor, esrc, nullptr, 0);
    k_fill<<<(n_com + 255) / 256, 256, 0, stream>>>(
        com_src, com_dst, n_com, cursor + NP, esrc, eidC, n_pub);
    k_fill<<<(n_ucu + 255) / 256, 256, 0, stream>>>(
        ucu_src, ucu_dst, n_ucu, cursor + 2 * NP, esrc, nullptr, 0);

    // ---- z = relu(LN(concat(h_user,user_ctx) @ W_conv + b_conv)) ----
    k_rowgemm<<<NU / 32, 256, 0, stream>>>(
        h_user, 128, W_conv, user_ctx, 64, W_conv + 128 * 128,
        1.f, 1.f, b_conv, 1.f, nullptr, 0.f, nullptr, zbuf);
    k_ln_relu<<<NU * 32 / 256, 256, 0, stream>>>(zbuf, ln_g, ln_b);

    // ---- gathers (register accumulation, one write per row) ----
    k_gather128<<<NP * 64 / 256, 256, 0, stream>>>(
        h_user, rptr, esrc, NP, out0, 0);
    k_gather_com<<<NP * 64 / 256, 256, 0, stream>>>(
        h_user, e_com, rptr + NP, esrc, eidC, n_pub, NP, out1, accE);
    k_gather128<<<NU * 64 / 256, 256, 0, stream>>>(
        zbuf, rptr + 2 * NP, esrc, NU, out2, 1);   // divide -> final user_new

    // ---- post_pub = (sum_pub @ W_pub)/deg + b_pub (0 if deg==0), in place ----
    k_rowgemm<<<NP / 32, 256, 0, stream>>>(
        out0, 128, W_pub, nullptr, 0, nullptr,
        1.f, 1.f, b_pub, 1.f, nullptr, 0.f, rptr, out0);

    // ---- post_com = (0.7*sumU@W_com + 0.3*sumE@W_ecom)/deg + 0.7*b_com + 0.3*b_ecom ----
    k_rowgemm<<<NP / 32, 256, 0, stream>>>(
        out1, 128, W_com, accE, 64, W_ecom,
        0.7f / 0.3f, 0.3f, b_com, 0.7f, b_ecom, 0.3f, rptr + NP, out1);
}

// Round 3
// 1078.434 us; speedup vs baseline: 7.0052x; 1.1432x over previous
//
#include <hip/hip_runtime.h>

typedef long long i64;
typedef unsigned int uint;

#define NU 100000
#define NP 100000
#define NSEG 300000   // pub counts [0,NP), com counts [NP,2NP), ucu counts [2NP,2NP+NU)

// ---------------- bf16 helpers ----------------
__device__ __forceinline__ uint f2b2(float x, float y) {
    uint ux = __float_as_uint(x), uy = __float_as_uint(y);
    ux = (ux + 0x7FFFu + ((ux >> 16) & 1u)) >> 16;
    uy = (uy + 0x7FFFu + ((uy >> 16) & 1u)) >> 16;
    return ux | (uy << 16);
}
__device__ __forceinline__ float blo(uint a) { return __uint_as_float(a << 16); }
__device__ __forceinline__ float bhi(uint a) { return __uint_as_float(a & 0xFFFF0000u); }

// convert f32 [n*4] -> bf16 pairs; one float4 -> uint2 per thread
__global__ __launch_bounds__(256) void k_cvt_bf16(
    const float* __restrict__ in, uint* __restrict__ out, int n4)
{
    int t = blockIdx.x * 256 + threadIdx.x;
    if (t >= n4) return;
    float4 v = *(const float4*)(in + (i64)t * 4);
    uint2 o; o.x = f2b2(v.x, v.y); o.y = f2b2(v.z, v.w);
    *(uint2*)(out + (i64)t * 2) = o;
}

// ---------------- CSR build ----------------
__global__ __launch_bounds__(256) void k_hist3(
    const int* __restrict__ d0, int n0, const int* __restrict__ d1, int n1,
    const int* __restrict__ d2, int n2, int* __restrict__ cnt)
{
    int e = blockIdx.x * 256 + threadIdx.x;
    if (e < n0) { atomicAdd(cnt + d0[e], 1); return; }
    e -= n0;
    if (e < n1) { atomicAdd(cnt + NP + d1[e], 1); return; }
    e -= n1;
    if (e < n2) atomicAdd(cnt + 2 * NP + d2[e], 1);
}

__global__ __launch_bounds__(1024) void k_scan_block(
    const int* __restrict__ in, int n, int* __restrict__ out, int* __restrict__ bsum)
{
    __shared__ int sm[1024];
    int gid = blockIdx.x * 1024 + threadIdx.x;
    int v = (gid < n) ? in[gid] : 0;
    sm[threadIdx.x] = v;
    __syncthreads();
    for (int off = 1; off < 1024; off <<= 1) {
        int t = (threadIdx.x >= (unsigned)off) ? sm[threadIdx.x - off] : 0;
        __syncthreads();
        sm[threadIdx.x] += t;
        __syncthreads();
    }
    if (gid < n) out[gid] = sm[threadIdx.x] - v;      // exclusive
    if (threadIdx.x == 1023) bsum[blockIdx.x] = sm[1023];
}

__global__ __launch_bounds__(512) void k_scan_bsum(int* __restrict__ bsum, int nb)
{
    __shared__ int sm[512];
    int v = (threadIdx.x < (unsigned)nb) ? bsum[threadIdx.x] : 0;
    sm[threadIdx.x] = v;
    __syncthreads();
    for (int off = 1; off < 512; off <<= 1) {
        int t = (threadIdx.x >= (unsigned)off) ? sm[threadIdx.x - off] : 0;
        __syncthreads();
        sm[threadIdx.x] += t;
        __syncthreads();
    }
    if (threadIdx.x < (unsigned)nb) bsum[threadIdx.x] = sm[threadIdx.x] - v;  // exclusive
}

__global__ __launch_bounds__(1024) void k_scan_add(
    int* __restrict__ rptr, int n, const int* __restrict__ bsum,
    int* __restrict__ cursor, int total)
{
    int gid = blockIdx.x * 1024 + threadIdx.x;
    if (gid < n) {
        int v = rptr[gid] + bsum[blockIdx.x];
        rptr[gid] = v;
        cursor[gid] = v;
    }
    if (gid == 0) rptr[n] = total;
}

__global__ __launch_bounds__(256) void k_fill3(
    const int* __restrict__ s0, const int* __restrict__ d0, int n0,
    const int* __restrict__ s1, const int* __restrict__ d1, int n1,
    const int* __restrict__ s2, const int* __restrict__ d2, int n2,
    int* __restrict__ cursor, int* __restrict__ esrc, int* __restrict__ eidC)
{
    int e = blockIdx.x * 256 + threadIdx.x;
    if (e < n0) {
        int pos = atomicAdd(cursor + d0[e], 1);
        esrc[pos] = s0[e];
        return;
    }
    e -= n0;
    if (e < n1) {
        int pos = atomicAdd(cursor + NP + d1[e], 1);
        esrc[pos] = s1[e];
        eidC[pos - n0] = e;          // com edges start at offset n0 in esrc
        return;
    }
    e -= n1;
    if (e < n2) {
        int pos = atomicAdd(cursor + 2 * NP + d2[e], 1);
        esrc[pos] = s2[e];
    }
}

// ---------------- CSR gathers (bf16 feature tables), one wave per row ----------------
__global__ __launch_bounds__(256) void k_gather128b(
    const uint* __restrict__ feat, const int* __restrict__ rp,
    const int* __restrict__ esrc, int nrow, float* __restrict__ out, int divide)
{
    int t = blockIdx.x * 256 + threadIdx.x;
    int row = t >> 6;
    if (row >= nrow) return;
    int lane = t & 63;
    int beg = rp[row], end = rp[row + 1];
    float ax = 0.f, ay = 0.f;
    int j = beg;
    for (; j + 3 < end; j += 4) {
        int s0 = esrc[j], s1 = esrc[j + 1], s2 = esrc[j + 2], s3 = esrc[j + 3];
        uint a0 = feat[(i64)s0 * 64 + lane];
        uint a1 = feat[(i64)s1 * 64 + lane];
        uint a2 = feat[(i64)s2 * 64 + lane];
        uint a3 = feat[(i64)s3 * 64 + lane];
        ax += (blo(a0) + blo(a1)) + (blo(a2) + blo(a3));
        ay += (bhi(a0) + bhi(a1)) + (bhi(a2) + bhi(a3));
    }
    for (; j < end; ++j) {
        uint a = feat[(i64)esrc[j] * 64 + lane];
        ax += blo(a); ay += bhi(a);
    }
    if (divide) {
        int deg = end - beg;
        float m = deg > 0 ? 1.f / (float)deg : 0.f;
        ax *= m; ay *= m;
    }
    float2 o; o.x = ax; o.y = ay;
    *(float2*)(out + (i64)row * 128 + lane * 2) = o;
}

__global__ __launch_bounds__(256) void k_gather_com(
    const uint* __restrict__ hu2, const float* __restrict__ ec,
    const int* __restrict__ rp, const int* __restrict__ esrc,
    const int* __restrict__ eid, int ebase, int nrow,
    float* __restrict__ outU, float* __restrict__ outE)
{
    int t = blockIdx.x * 256 + threadIdx.x;
    int row = t >> 6;
    if (row >= nrow) return;
    int lane = t & 63;
    int beg = rp[row], end = rp[row + 1];
    float ax = 0.f, ay = 0.f, aE = 0.f;
    int j = beg;
    for (; j + 3 < end; j += 4) {
        int s0 = esrc[j], s1 = esrc[j + 1], s2 = esrc[j + 2], s3 = esrc[j + 3];
        int e0 = eid[j - ebase], e1 = eid[j + 1 - ebase];
        int e2 = eid[j + 2 - ebase], e3 = eid[j + 3 - ebase];
        uint a0 = hu2[(i64)s0 * 64 + lane];
        uint a1 = hu2[(i64)s1 * 64 + lane];
        uint a2 = hu2[(i64)s2 * 64 + lane];
        uint a3 = hu2[(i64)s3 * 64 + lane];
        float f0 = ec[(i64)e0 * 64 + lane], f1 = ec[(i64)e1 * 64 + lane];
        float f2 = ec[(i64)e2 * 64 + lane], f3 = ec[(i64)e3 * 64 + lane];
        ax += (blo(a0) + blo(a1)) + (blo(a2) + blo(a3));
        ay += (bhi(a0) + bhi(a1)) + (bhi(a2) + bhi(a3));
        aE += (f0 + f1) + (f2 + f3);
    }
    for (; j < end; ++j) {
        uint a = hu2[(i64)esrc[j] * 64 + lane];
        ax += blo(a); ay += bhi(a);
        aE += ec[(i64)eid[j - ebase] * 64 + lane];
    }
    float2 o; o.x = ax; o.y = ay;
    *(float2*)(outU + (i64)row * 128 + lane * 2) = o;
    outE[(i64)row * 64 + lane] = aE;
}

// ---------------- z-GEMM fused with LayerNorm+ReLU, bf16 output ----------------
// thread tile: 4 users x 4 features; lanes 0-31 / 32-63 each own 4 users.
__global__ __launch_bounds__(256) void k_zgemm_ln(
    const float* __restrict__ hu, const float* __restrict__ ctx,
    const float* __restrict__ W, const float* __restrict__ bias,
    const float* __restrict__ ln_g, const float* __restrict__ ln_b,
    uint* __restrict__ zout)
{
    const int fg = threadIdx.x & 31;
    const int ug = threadIdx.x >> 5;
    const int u0 = blockIdx.x * 32 + ug * 4;

    float acc[4][4];
#pragma unroll
    for (int i = 0; i < 4; ++i)
#pragma unroll
        for (int q = 0; q < 4; ++q) acc[i][q] = 0.f;

    // h_user part (K=128)
    {
        const float* xr0 = hu + (i64)(u0 + 0) * 128;
        const float* xr1 = hu + (i64)(u0 + 1) * 128;
        const float* xr2 = hu + (i64)(u0 + 2) * 128;
        const float* xr3 = hu + (i64)(u0 + 3) * 128;
        for (int k = 0; k < 128; k += 4) {
            float xa[4], xb[4], xc[4], xd[4];
            *(float4*)xa = *(const float4*)(xr0 + k);
            *(float4*)xb = *(const float4*)(xr1 + k);
            *(float4*)xc = *(const float4*)(xr2 + k);
            *(float4*)xd = *(const float4*)(xr3 + k);
#pragma unroll
            for (int jj = 0; jj < 4; ++jj) {
                float w[4];
                *(float4*)w = *(const float4*)(W + (i64)(k + jj) * 128 + fg * 4);
#pragma unroll
                for (int q = 0; q < 4; ++q) {
                    acc[0][q] = fmaf(xa[jj], w[q], acc[0][q]);
                    acc[1][q] = fmaf(xb[jj], w[q], acc[1][q]);
                    acc[2][q] = fmaf(xc[jj], w[q], acc[2][q]);
                    acc[3][q] = fmaf(xd[jj], w[q], acc[3][q]);
                }
            }
        }
    }
    // ctx part (K=64), W rows 128..191
    {
        const float* xr0 = ctx + (i64)(u0 + 0) * 64;
        const float* xr1 = ctx + (i64)(u0 + 1) * 64;
        const float* xr2 = ctx + (i64)(u0 + 2) * 64;
        const float* xr3 = ctx + (i64)(u0 + 3) * 64;
        const float* W2 = W + (i64)128 * 128;
        for (int k = 0; k < 64; k += 4) {
            float xa[4], xb[4], xc[4], xd[4];
            *(float4*)xa = *(const float4*)(xr0 + k);
            *(float4*)xb = *(const float4*)(xr1 + k);
            *(float4*)xc = *(const float4*)(xr2 + k);
            *(float4*)xd = *(const float4*)(xr3 + k);
#pragma unroll
            for (int jj = 0; jj < 4; ++jj) {
                float w[4];
                *(float4*)w = *(const float4*)(W2 + (i64)(k + jj) * 128 + fg * 4);
#pragma unroll
                for (int q = 0; q < 4; ++q) {
                    acc[0][q] = fmaf(xa[jj], w[q], acc[0][q]);
                    acc[1][q] = fmaf(xb[jj], w[q], acc[1][q]);
                    acc[2][q] = fmaf(xc[jj], w[q], acc[2][q]);
                    acc[3][q] = fmaf(xd[jj], w[q], acc[3][q]);
                }
            }
        }
    }

    float bv[4], gg[4], bb[4];
    *(float4*)bv = *(const float4*)(bias + fg * 4);
    *(float4*)gg = *(const float4*)(ln_g + fg * 4);
    *(float4*)bb = *(const float4*)(ln_b + fg * 4);

#pragma unroll
    for (int i = 0; i < 4; ++i) {
        float v[4];
#pragma unroll
        for (int q = 0; q < 4; ++q) v[q] = acc[i][q] + bv[q];
        float s = (v[0] + v[1]) + (v[2] + v[3]);
#pragma unroll
        for (int m = 1; m < 32; m <<= 1) s += __shfl_xor(s, m, 32);
        float mu = s * (1.f / 128.f);
        float d[4];
#pragma unroll
        for (int q = 0; q < 4; ++q) d[q] = v[q] - mu;
        float sq = (d[0] * d[0] + d[1] * d[1]) + (d[2] * d[2] + d[3] * d[3]);
#pragma unroll
        for (int m = 1; m < 32; m <<= 1) sq += __shfl_xor(sq, m, 32);
        float rs = rsqrtf(sq * (1.f / 128.f) + 1e-5f);
        float o[4];
#pragma unroll
        for (int q = 0; q < 4; ++q) o[q] = fmaxf(0.f, d[q] * rs * gg[q] + bb[q]);
        uint2 z2; z2.x = f2b2(o[0], o[1]); z2.y = f2b2(o[2], o[3]);
        *(uint2*)(zout + (i64)(u0 + i) * 64 + fg * 2) = z2;
    }
}

// ---------------- rowwise GEMM: out[u] = sfin*( segratio*X0@W0 + X1@W1 )/deg + bias ----
__device__ __forceinline__ void seg_accum(const float* __restrict__ X, int K,
        const float* __restrict__ W, int u0, int fg, float acc[4][4])
{
    const float* xr0 = X + (i64)(u0 + 0) * K;
    const float* xr1 = X + (i64)(u0 + 1) * K;
    const float* xr2 = X + (i64)(u0 + 2) * K;
    const float* xr3 = X + (i64)(u0 + 3) * K;
    for (int k = 0; k < K; k += 4) {
        float xa[4], xb[4], xc[4], xd[4];
        *(float4*)xa = *(const float4*)(xr0 + k);
        *(float4*)xb = *(const float4*)(xr1 + k);
        *(float4*)xc = *(const float4*)(xr2 + k);
        *(float4*)xd = *(const float4*)(xr3 + k);
#pragma unroll
        for (int j = 0; j < 4; ++j) {
            float w[4];
            *(float4*)w = *(const float4*)(W + (i64)(k + j) * 128 + fg * 4);
#pragma unroll
            for (int q = 0; q < 4; ++q) {
                acc[0][q] = fmaf(xa[j], w[q], acc[0][q]);
                acc[1][q] = fmaf(xb[j], w[q], acc[1][q]);
                acc[2][q] = fmaf(xc[j], w[q], acc[2][q]);
                acc[3][q] = fmaf(xd[j], w[q], acc[3][q]);
            }
        }
    }
}

__global__ __launch_bounds__(256) void k_rowgemm(
    const float* __restrict__ X0, int K0, const float* __restrict__ W0,
    const float* __restrict__ X1, int K1, const float* __restrict__ W1,
    float segratio, float sfin,
    const float* __restrict__ b0, float bs0,
    const float* __restrict__ b1, float bs1,
    const int* __restrict__ rp, float* __restrict__ out)
{
    const int fg = threadIdx.x & 31;
    const int ug = threadIdx.x >> 5;
    const int u0 = blockIdx.x * 32 + ug * 4;

    float acc[4][4];
#pragma unroll
    for (int i = 0; i < 4; ++i)
#pragma unroll
        for (int q = 0; q < 4; ++q) acc[i][q] = 0.f;

    seg_accum(X0, K0, W0, u0, fg, acc);
    if (K1 > 0) {
        if (segratio != 1.0f) {
#pragma unroll
            for (int i = 0; i < 4; ++i)
#pragma unroll
                for (int q = 0; q < 4; ++q) acc[i][q] *= segratio;
        }
        seg_accum(X1, K1, W1, u0, fg, acc);
    }

    float bv[4] = {0.f, 0.f, 0.f, 0.f};
    if (b0) {
        float tb[4]; *(float4*)tb = *(const float4*)(b0 + fg * 4);
#pragma unroll
        for (int q = 0; q < 4; ++q) bv[q] = fmaf(bs0, tb[q], bv[q]);
    }
    if (b1) {
        float tb[4]; *(float4*)tb = *(const float4*)(b1 + fg * 4);
#pragma unroll
        for (int q = 0; q < 4; ++q) bv[q] = fmaf(bs1, tb[q], bv[q]);
    }

#pragma unroll
    for (int i = 0; i < 4; ++i) {
        float o[4];
        int deg = rp[u0 + i + 1] - rp[u0 + i];
        if (deg > 0) {
            float m = sfin / (float)deg;
#pragma unroll
            for (int q = 0; q < 4; ++q) o[q] = fmaf(acc[i][q], m, bv[q]);
        } else {
#pragma unroll
            for (int q = 0; q < 4; ++q) o[q] = 0.f;
        }
        *(float4*)(out + (i64)(u0 + i) * 128 + fg * 4) = *(float4*)o;
    }
}

extern "C" void kernel_launch(void* const* d_in, const int* in_sizes, int n_in,
                              void* d_out, int out_size, void* d_ws, size_t ws_size,
                              hipStream_t stream)
{
    const float* h_user   = (const float*)d_in[0];
    const float* user_ctx = (const float*)d_in[2];
    const float* e_com    = (const float*)d_in[3];
    const int* pub_src = (const int*)d_in[4];
    const int* pub_dst = (const int*)d_in[5];
    const int* com_src = (const int*)d_in[6];
    const int* com_dst = (const int*)d_in[7];
    const int* ucu_src = (const int*)d_in[8];
    const int* ucu_dst = (const int*)d_in[9];
    const float* W_pub  = (const float*)d_in[10];
    const float* b_pub  = (const float*)d_in[11];
    const float* W_com  = (const float*)d_in[12];
    const float* b_com  = (const float*)d_in[13];
    const float* W_conv = (const float*)d_in[14];
    const float* b_conv = (const float*)d_in[15];
    const float* ln_g   = (const float*)d_in[16];
    const float* ln_b   = (const float*)d_in[17];
    const float* W_ecom = (const float*)d_in[18];
    const float* b_ecom = (const float*)d_in[19];

    const int n_pub = in_sizes[4];
    const int n_com = in_sizes[6];
    const int n_ucu = in_sizes[8];
    const int total = n_pub + n_com + n_ucu;

    float* out0 = (float*)d_out;              // sum_pub  -> post_pub (in-place gemm)
    float* out1 = out0 + (i64)NP * 128;       // sum_comU -> post_com (in-place gemm)
    float* out2 = out1 + (i64)NP * 128;       // user_new (final, written by gather)

    char* ws = (char*)d_ws;
    uint* hu2   = (uint*)ws;                                  // NU*64 dwords (bf16 pairs)
    uint* zbuf  = hu2 + (i64)NU * 64;                         // NU*64 dwords (bf16 pairs)
    float* accE = (float*)(zbuf + (i64)NU * 64);              // NP*64 f32
    int* cnt    = (int*)(accE + (i64)NP * 64);                // NSEG
    int* rptr   = cnt + NSEG;                                 // NSEG+1
    int* cursor = rptr + NSEG + 1;                            // NSEG
    int* bsum   = cursor + NSEG;                              // 512
    int* esrc   = bsum + 512;                                 // total
    int* eidC   = esrc + total;                               // n_com

    const int NB = (NSEG + 1023) / 1024;

    // ---- CSR build + bf16 conversion (independent streams of work) ----
    hipMemsetAsync(cnt, 0, (size_t)NSEG * 4, stream);
    k_cvt_bf16<<<(NU * 32 + 255) / 256, 256, 0, stream>>>(h_user, hu2, NU * 32);
    k_hist3<<<(total + 255) / 256, 256, 0, stream>>>(
        pub_dst, n_pub, com_dst, n_com, ucu_dst, n_ucu, cnt);
    k_scan_block<<<NB, 1024, 0, stream>>>(cnt, NSEG, rptr, bsum);
    k_scan_bsum<<<1, 512, 0, stream>>>(bsum, NB);
    k_scan_add<<<NB, 1024, 0, stream>>>(rptr, NSEG, bsum, cursor, total);
    k_fill3<<<(total + 255) / 256, 256, 0, stream>>>(
        pub_src, pub_dst, n_pub, com_src, com_dst, n_com,
        ucu_src, ucu_dst, n_ucu, cursor, esrc, eidC);

    // ---- z = relu(LN(concat(h_user,user_ctx) @ W_conv + b_conv)) -> bf16 zbuf ----
    k_zgemm_ln<<<NU / 32, 256, 0, stream>>>(
        h_user, user_ctx, W_conv, b_conv, ln_g, ln_b, zbuf);

    // ---- gathers (register accumulation, one write per row) ----
    k_gather_com<<<NP * 64 / 256, 256, 0, stream>>>(
        hu2, e_com, rptr + NP, esrc, eidC, n_pub, NP, out1, accE);
    k_gather128b<<<NU * 64 / 256, 256, 0, stream>>>(
        zbuf, rptr + 2 * NP, esrc, NU, out2, 1);   // divide -> final user_new
    k_gather128b<<<NP * 64 / 256, 256, 0, stream>>>(
        hu2, rptr, esrc, NP, out0, 0);

    // ---- post_pub = (sum_pub @ W_pub)/deg + b_pub (0 if deg==0), in place ----
    k_rowgemm<<<NP / 32, 256, 0, stream>>>(
        out0, 128, W_pub, nullptr, 0, nullptr,
        1.f, 1.f, b_pub, 1.f, nullptr, 0.f, rptr, out0);

    // ---- post_com = (0.7*sumU@W_com + 0.3*sumE@W_ecom)/deg + 0.7*b_com + 0.3*b_ecom ----
    k_rowgemm<<<NP / 32, 256, 0, stream>>>(
        out1, 128, W_com, accE, 64, W_ecom,
        0.7f / 0.3f, 0.3f, b_com, 0.7f, b_ecom, 0.3f, rptr + NP, out1);
}

// Round 4
// 987.001 us; speedup vs baseline: 7.6541x; 1.0926x over previous
//
#include <hip/hip_runtime.h>

typedef long long i64;
typedef unsigned int uint;
typedef unsigned long long u64;

#define NU 100000
#define NP 100000
#define NSEG 300000   // pub dst' [0,NP), com [NP,2NP), ucu [2NP,2NP+NU)
#define LBKT 11
#define NBKT 160      // ceil(300000/2048)=147 used

// ---------------- bf16 helpers ----------------
__device__ __forceinline__ uint f2b2(float x, float y) {
    uint ux = __float_as_uint(x), uy = __float_as_uint(y);
    ux = (ux + 0x7FFFu + ((ux >> 16) & 1u)) >> 16;
    uy = (uy + 0x7FFFu + ((uy >> 16) & 1u)) >> 16;
    return ux | (uy << 16);
}
__device__ __forceinline__ float blo(uint a) { return __uint_as_float(a << 16); }
__device__ __forceinline__ float bhi(uint a) { return __uint_as_float(a & 0xFFFF0000u); }

__global__ __launch_bounds__(256) void k_cvt_bf16(
    const float* __restrict__ in, uint* __restrict__ out, int n4)
{
    int t = blockIdx.x * 256 + threadIdx.x;
    if (t >= n4) return;
    float4 v = *(const float4*)(in + (i64)t * 4);
    uint2 o; o.x = f2b2(v.x, v.y); o.y = f2b2(v.z, v.w);
    *(uint2*)(out + (i64)t * 2) = o;
}

// ---------------- CSR build ----------------
__global__ __launch_bounds__(256) void k_hist3(
    const int* __restrict__ d0, int n0, const int* __restrict__ d1, int n1,
    const int* __restrict__ d2, int n2, int* __restrict__ cnt)
{
    int e = blockIdx.x * 256 + threadIdx.x;
    if (e < n0) { atomicAdd(cnt + d0[e], 1); return; }
    e -= n0;
    if (e < n1) { atomicAdd(cnt + NP + d1[e], 1); return; }
    e -= n1;
    if (e < n2) atomicAdd(cnt + 2 * NP + d2[e], 1);
}

__global__ __launch_bounds__(1024) void k_scan_block(
    const int* __restrict__ in, int n, int* __restrict__ out, int* __restrict__ bsum)
{
    __shared__ int sm[1024];
    int gid = blockIdx.x * 1024 + threadIdx.x;
    int v = (gid < n) ? in[gid] : 0;
    sm[threadIdx.x] = v;
    __syncthreads();
    for (int off = 1; off < 1024; off <<= 1) {
        int t = (threadIdx.x >= (unsigned)off) ? sm[threadIdx.x - off] : 0;
        __syncthreads();
        sm[threadIdx.x] += t;
        __syncthreads();
    }
    if (gid < n) out[gid] = sm[threadIdx.x] - v;      // exclusive
    if (threadIdx.x == 1023) bsum[blockIdx.x] = sm[1023];
}

__global__ __launch_bounds__(512) void k_scan_bsum(int* __restrict__ bsum, int nb)
{
    __shared__ int sm[512];
    int v = (threadIdx.x < (unsigned)nb) ? bsum[threadIdx.x] : 0;
    sm[threadIdx.x] = v;
    __syncthreads();
    for (int off = 1; off < 512; off <<= 1) {
        int t = (threadIdx.x >= (unsigned)off) ? sm[threadIdx.x - off] : 0;
        __syncthreads();
        sm[threadIdx.x] += t;
        __syncthreads();
    }
    if (threadIdx.x < (unsigned)nb) bsum[threadIdx.x] = sm[threadIdx.x] - v;  // exclusive
}

__global__ __launch_bounds__(1024) void k_scan_add(
    int* __restrict__ rptr, int n, const int* __restrict__ bsum,
    int* __restrict__ cursor, int* __restrict__ gcur, int total)
{
    int gid = blockIdx.x * 1024 + threadIdx.x;
    if (gid < n) {
        int v = rptr[gid] + bsum[blockIdx.x];
        rptr[gid] = v;
        cursor[gid] = v;
        if ((gid & 2047) == 0) gcur[gid >> LBKT] = v;  // bucket base cursors
    }
    if (gid == 0) rptr[n] = total;
}

// pass A: bucket records (src|dst'<<17|eid<<36) into 2048-dst buckets, coalesced-ish runs
#define TILE_A 4096
__global__ __launch_bounds__(256) void k_bucketA(
    const int* __restrict__ ps, const int* __restrict__ pd, int n0,
    const int* __restrict__ cs, const int* __restrict__ cd, int n1,
    const int* __restrict__ us, const int* __restrict__ ud, int n2,
    int* __restrict__ gcur, u64* __restrict__ recs, int total)
{
    __shared__ int hist[NBKT];
    __shared__ int base[NBKT];
    int t0 = blockIdx.x * TILE_A;
    for (int i = threadIdx.x; i < NBKT; i += 256) hist[i] = 0;
    __syncthreads();
    u64 rec[16];
    int bkt[16];
#pragma unroll
    for (int i = 0; i < 16; ++i) {
        int e = t0 + i * 256 + threadIdx.x;
        if (e < total) {
            int src, dp, eid;
            if (e < n0) { src = ps[e]; dp = pd[e]; eid = 0; }
            else if (e < n0 + n1) { int le = e - n0; src = cs[le]; dp = NP + cd[le]; eid = le; }
            else { int le = e - n0 - n1; src = us[le]; dp = 2 * NP + ud[le]; eid = 0; }
            rec[i] = (u64)src | ((u64)dp << 17) | ((u64)eid << 36);
            bkt[i] = dp >> LBKT;
            atomicAdd(&hist[bkt[i]], 1);
        } else bkt[i] = -1;
    }
    __syncthreads();
    for (int i = threadIdx.x; i < NBKT; i += 256) {
        int h = hist[i];
        base[i] = h ? atomicAdd(gcur + i, h) : 0;
    }
    __syncthreads();
    for (int i = threadIdx.x; i < NBKT; i += 256) hist[i] = 0;
    __syncthreads();
#pragma unroll
    for (int i = 0; i < 16; ++i) {
        if (bkt[i] >= 0) {
            int r = atomicAdd(&hist[bkt[i]], 1);
            recs[(i64)base[bkt[i]] + r] = rec[i];
        }
    }
}

// pass B: exact per-dst scatter, bucket-localized writes/atomics
__global__ __launch_bounds__(256) void k_fillB(
    const u64* __restrict__ recs, int total, int n0,
    int* __restrict__ cursor, int* __restrict__ esrc4, u64* __restrict__ rec8)
{
    int p = blockIdx.x * 256 + threadIdx.x;
    if (p >= total) return;
    u64 rec = recs[p];
    int src = (int)(rec & 0x1FFFF);
    int dp  = (int)((rec >> 17) & 0x7FFFF);
    int eid = (int)(rec >> 36);
    int q = atomicAdd(cursor + dp, 1);
    if (dp >= NP && dp < 2 * NP) rec8[q - n0] = (u64)(uint)src | ((u64)(uint)eid << 32);
    else esrc4[q] = src;
}

// ---------------- CSR gathers (bf16 tables), one wave per row, 8-wide MLP ----------------
__global__ __launch_bounds__(256) void k_gather128b(
    const uint* __restrict__ feat, const int* __restrict__ rp,
    const int* __restrict__ esrc, int nrow, float* __restrict__ out, int divide)
{
    int t = blockIdx.x * 256 + threadIdx.x;
    int row = t >> 6;
    if (row >= nrow) return;
    int lane = t & 63;
    int beg = rp[row], end = rp[row + 1];
    float ax = 0.f, ay = 0.f;
    int j = beg;
    for (; j + 8 <= end; j += 8) {
        int s[8];
#pragma unroll
        for (int k = 0; k < 8; ++k) s[k] = esrc[j + k];
        uint a[8];
#pragma unroll
        for (int k = 0; k < 8; ++k) a[k] = feat[(i64)s[k] * 64 + lane];
#pragma unroll
        for (int k = 0; k < 8; ++k) { ax += blo(a[k]); ay += bhi(a[k]); }
    }
    if (j < end) {
        int rem = end - j;
        int s[8]; uint a[8];
#pragma unroll
        for (int k = 0; k < 8; ++k) s[k] = esrc[min(j + k, end - 1)];
#pragma unroll
        for (int k = 0; k < 8; ++k) a[k] = feat[(i64)s[k] * 64 + lane];
#pragma unroll
        for (int k = 0; k < 8; ++k) {
            float m = (k < rem) ? 1.f : 0.f;
            ax = fmaf(m, blo(a[k]), ax); ay = fmaf(m, bhi(a[k]), ay);
        }
    }
    if (divide) {
        int deg = end - beg;
        float mm = deg > 0 ? 1.f / (float)deg : 0.f;
        ax *= mm; ay *= mm;
    }
    float2 o; o.x = ax; o.y = ay;
    *(float2*)(out + (i64)row * 128 + lane * 2) = o;
}

__global__ __launch_bounds__(256) void k_gather_com(
    const uint* __restrict__ hu2, const float* __restrict__ ec,
    const int* __restrict__ rp, const u64* __restrict__ rec8, int ebase, int nrow,
    float* __restrict__ outU, float* __restrict__ outE)
{
    int t = blockIdx.x * 256 + threadIdx.x;
    int row = t >> 6;
    if (row >= nrow) return;
    int lane = t & 63;
    int beg = rp[row], end = rp[row + 1];
    float ax = 0.f, ay = 0.f, aE = 0.f;
    int j = beg;
    for (; j + 8 <= end; j += 8) {
        u64 r[8];
#pragma unroll
        for (int k = 0; k < 8; ++k) r[k] = rec8[j + k - ebase];
        uint a[8]; float f[8];
#pragma unroll
        for (int k = 0; k < 8; ++k) {
            int s = (int)(uint)r[k];
            int e = (int)(r[k] >> 32);
            a[k] = hu2[(i64)s * 64 + lane];
            f[k] = ec[(i64)e * 64 + lane];
        }
#pragma unroll
        for (int k = 0; k < 8; ++k) { ax += blo(a[k]); ay += bhi(a[k]); aE += f[k]; }
    }
    if (j < end) {
        int rem = end - j;
        u64 r[8];
#pragma unroll
        for (int k = 0; k < 8; ++k) r[k] = rec8[min(j + k, end - 1) - ebase];
        uint a[8]; float f[8];
#pragma unroll
        for (int k = 0; k < 8; ++k) {
            int s = (int)(uint)r[k];
            int e = (int)(r[k] >> 32);
            a[k] = hu2[(i64)s * 64 + lane];
            f[k] = ec[(i64)e * 64 + lane];
        }
#pragma unroll
        for (int k = 0; k < 8; ++k) {
            float m = (k < rem) ? 1.f : 0.f;
            ax = fmaf(m, blo(a[k]), ax); ay = fmaf(m, bhi(a[k]), ay);
            aE = fmaf(m, f[k], aE);
        }
    }
    float2 o; o.x = ax; o.y = ay;
    *(float2*)(outU + (i64)row * 128 + lane * 2) = o;
    outE[(i64)row * 64 + lane] = aE;
}

// ---------------- z-GEMM fused with LayerNorm+ReLU, bf16 output ----------------
__global__ __launch_bounds__(256) void k_zgemm_ln(
    const float* __restrict__ hu, const float* __restrict__ ctx,
    const float* __restrict__ W, const float* __restrict__ bias,
    const float* __restrict__ ln_g, const float* __restrict__ ln_b,
    uint* __restrict__ zout)
{
    const int fg = threadIdx.x & 31;
    const int ug = threadIdx.x >> 5;
    const int u0 = blockIdx.x * 32 + ug * 4;

    float acc[4][4];
#pragma unroll
    for (int i = 0; i < 4; ++i)
#pragma unroll
        for (int q = 0; q < 4; ++q) acc[i][q] = 0.f;

    {
        const float* xr0 = hu + (i64)(u0 + 0) * 128;
        const float* xr1 = hu + (i64)(u0 + 1) * 128;
        const float* xr2 = hu + (i64)(u0 + 2) * 128;
        const float* xr3 = hu + (i64)(u0 + 3) * 128;
        for (int k = 0; k < 128; k += 4) {
            float xa[4], xb[4], xc[4], xd[4];
            *(float4*)xa = *(const float4*)(xr0 + k);
            *(float4*)xb = *(const float4*)(xr1 + k);
            *(float4*)xc = *(const float4*)(xr2 + k);
            *(float4*)xd = *(const float4*)(xr3 + k);
#pragma unroll
            for (int jj = 0; jj < 4; ++jj) {
                float w[4];
                *(float4*)w = *(const float4*)(W + (i64)(k + jj) * 128 + fg * 4);
#pragma unroll
                for (int q = 0; q < 4; ++q) {
                    acc[0][q] = fmaf(xa[jj], w[q], acc[0][q]);
                    acc[1][q] = fmaf(xb[jj], w[q], acc[1][q]);
                    acc[2][q] = fmaf(xc[jj], w[q], acc[2][q]);
                    acc[3][q] = fmaf(xd[jj], w[q], acc[3][q]);
                }
            }
        }
    }
    {
        const float* xr0 = ctx + (i64)(u0 + 0) * 64;
        const float* xr1 = ctx + (i64)(u0 + 1) * 64;
        const float* xr2 = ctx + (i64)(u0 + 2) * 64;
        const float* xr3 = ctx + (i64)(u0 + 3) * 64;
        const float* W2 = W + (i64)128 * 128;
        for (int k = 0; k < 64; k += 4) {
            float xa[4], xb[4], xc[4], xd[4];
            *(float4*)xa = *(const float4*)(xr0 + k);
            *(float4*)xb = *(const float4*)(xr1 + k);
            *(float4*)xc = *(const float4*)(xr2 + k);
            *(float4*)xd = *(const float4*)(xr3 + k);
#pragma unroll
            for (int jj = 0; jj < 4; ++jj) {
                float w[4];
                *(float4*)w = *(const float4*)(W2 + (i64)(k + jj) * 128 + fg * 4);
#pragma unroll
                for (int q = 0; q < 4; ++q) {
                    acc[0][q] = fmaf(xa[jj], w[q], acc[0][q]);
                    acc[1][q] = fmaf(xb[jj], w[q], acc[1][q]);
                    acc[2][q] = fmaf(xc[jj], w[q], acc[2][q]);
                    acc[3][q] = fmaf(xd[jj], w[q], acc[3][q]);
                }
            }
        }
    }

    float bv[4], gg[4], bb[4];
    *(float4*)bv = *(const float4*)(bias + fg * 4);
    *(float4*)gg = *(const float4*)(ln_g + fg * 4);
    *(float4*)bb = *(const float4*)(ln_b + fg * 4);

#pragma unroll
    for (int i = 0; i < 4; ++i) {
        float v[4];
#pragma unroll
        for (int q = 0; q < 4; ++q) v[q] = acc[i][q] + bv[q];
        float s = (v[0] + v[1]) + (v[2] + v[3]);
#pragma unroll
        for (int m = 1; m < 32; m <<= 1) s += __shfl_xor(s, m, 32);
        float mu = s * (1.f / 128.f);
        float d[4];
#pragma unroll
        for (int q = 0; q < 4; ++q) d[q] = v[q] - mu;
        float sq = (d[0] * d[0] + d[1] * d[1]) + (d[2] * d[2] + d[3] * d[3]);
#pragma unroll
        for (int m = 1; m < 32; m <<= 1) sq += __shfl_xor(sq, m, 32);
        float rs = rsqrtf(sq * (1.f / 128.f) + 1e-5f);
        float o[4];
#pragma unroll
        for (int q = 0; q < 4; ++q) o[q] = fmaxf(0.f, d[q] * rs * gg[q] + bb[q]);
        uint2 z2; z2.x = f2b2(o[0], o[1]); z2.y = f2b2(o[2], o[3]);
        *(uint2*)(zout + (i64)(u0 + i) * 64 + fg * 2) = z2;
    }
}

// ---------------- rowwise GEMM: out[u] = sfin*( segratio*X0@W0 + X1@W1 )/deg + bias ----
__device__ __forceinline__ void seg_accum(const float* __restrict__ X, int K,
        const float* __restrict__ W, int u0, int fg, float acc[4][4])
{
    const float* xr0 = X + (i64)(u0 + 0) * K;
    const float* xr1 = X + (i64)(u0 + 1) * K;
    const float* xr2 = X + (i64)(u0 + 2) * K;
    const float* xr3 = X + (i64)(u0 + 3) * K;
    for (int k = 0; k < K; k += 4) {
        float xa[4], xb[4], xc[4], xd[4];
        *(float4*)xa = *(const float4*)(xr0 + k);
        *(float4*)xb = *(const float4*)(xr1 + k);
        *(float4*)xc = *(const float4*)(xr2 + k);
        *(float4*)xd = *(const float4*)(xr3 + k);
#pragma unroll
        for (int j = 0; j < 4; ++j) {
            float w[4];
            *(float4*)w = *(const float4*)(W + (i64)(k + j) * 128 + fg * 4);
#pragma unroll
            for (int q = 0; q < 4; ++q) {
                acc[0][q] = fmaf(xa[j], w[q], acc[0][q]);
                acc[1][q] = fmaf(xb[j], w[q], acc[1][q]);
                acc[2][q] = fmaf(xc[j], w[q], acc[2][q]);
                acc[3][q] = fmaf(xd[j], w[q], acc[3][q]);
            }
        }
    }
}

__global__ __launch_bounds__(256) void k_rowgemm(
    const float* __restrict__ X0, int K0, const float* __restrict__ W0,
    const float* __restrict__ X1, int K1, const float* __restrict__ W1,
    float segratio, float sfin,
    const float* __restrict__ b0, float bs0,
    const float* __restrict__ b1, float bs1,
    const int* __restrict__ rp, float* __restrict__ out)
{
    const int fg = threadIdx.x & 31;
    const int ug = threadIdx.x >> 5;
    const int u0 = blockIdx.x * 32 + ug * 4;

    float acc[4][4];
#pragma unroll
    for (int i = 0; i < 4; ++i)
#pragma unroll
        for (int q = 0; q < 4; ++q) acc[i][q] = 0.f;

    seg_accum(X0, K0, W0, u0, fg, acc);
    if (K1 > 0) {
        if (segratio != 1.0f) {
#pragma unroll
            for (int i = 0; i < 4; ++i)
#pragma unroll
                for (int q = 0; q < 4; ++q) acc[i][q] *= segratio;
        }
        seg_accum(X1, K1, W1, u0, fg, acc);
    }

    float bv[4] = {0.f, 0.f, 0.f, 0.f};
    if (b0) {
        float tb[4]; *(float4*)tb = *(const float4*)(b0 + fg * 4);
#pragma unroll
        for (int q = 0; q < 4; ++q) bv[q] = fmaf(bs0, tb[q], bv[q]);
    }
    if (b1) {
        float tb[4]; *(float4*)tb = *(const float4*)(b1 + fg * 4);
#pragma unroll
        for (int q = 0; q < 4; ++q) bv[q] = fmaf(bs1, tb[q], bv[q]);
    }

#pragma unroll
    for (int i = 0; i < 4; ++i) {
        float o[4];
        int deg = rp[u0 + i + 1] - rp[u0 + i];
        if (deg > 0) {
            float m = sfin / (float)deg;
#pragma unroll
            for (int q = 0; q < 4; ++q) o[q] = fmaf(acc[i][q], m, bv[q]);
        } else {
#pragma unroll
            for (int q = 0; q < 4; ++q) o[q] = 0.f;
        }
        *(float4*)(out + (i64)(u0 + i) * 128 + fg * 4) = *(float4*)o;
    }
}

extern "C" void kernel_launch(void* const* d_in, const int* in_sizes, int n_in,
                              void* d_out, int out_size, void* d_ws, size_t ws_size,
                              hipStream_t stream)
{
    const float* h_user   = (const float*)d_in[0];
    const float* user_ctx = (const float*)d_in[2];
    const float* e_com    = (const float*)d_in[3];
    const int* pub_src = (const int*)d_in[4];
    const int* pub_dst = (const int*)d_in[5];
    const int* com_src = (const int*)d_in[6];
    const int* com_dst = (const int*)d_in[7];
    const int* ucu_src = (const int*)d_in[8];
    const int* ucu_dst = (const int*)d_in[9];
    const float* W_pub  = (const float*)d_in[10];
    const float* b_pub  = (const float*)d_in[11];
    const float* W_com  = (const float*)d_in[12];
    const float* b_com  = (const float*)d_in[13];
    const float* W_conv = (const float*)d_in[14];
    const float* b_conv = (const float*)d_in[15];
    const float* ln_g   = (const float*)d_in[16];
    const float* ln_b   = (const float*)d_in[17];
    const float* W_ecom = (const float*)d_in[18];
    const float* b_ecom = (const float*)d_in[19];

    const int n_pub = in_sizes[4];
    const int n_com = in_sizes[6];
    const int n_ucu = in_sizes[8];
    const int total = n_pub + n_com + n_ucu;

    float* out0 = (float*)d_out;
    float* out1 = out0 + (i64)NP * 128;
    float* out2 = out1 + (i64)NP * 128;

    // ---- ws layout (bytes), zbuf overlays recsA (dead after k_fillB) ----
    char* ws = (char*)d_ws;
    i64 off = 0;
    uint* hu2 = (uint*)(ws + off);      off += (i64)NU * 64 * 4;
    i64 reg2 = off;                     // union { recsA : total u64 ; zbuf : NU*64 uint }
    u64* recsA = (u64*)(ws + reg2);
    uint* zbuf = (uint*)(ws + reg2);
    i64 reg2_sz = (i64)total * 8 > (i64)NU * 64 * 4 ? (i64)total * 8 : (i64)NU * 64 * 4;
    off += (reg2_sz + 7) & ~7LL;
    float* accE = (float*)(ws + off);   off += (i64)NP * 64 * 4;
    u64* rec8 = (u64*)(ws + off);       off += (i64)n_com * 8;
    int* cnt    = (int*)(ws + off);     off += (i64)NSEG * 4;
    int* rptr   = (int*)(ws + off);     off += (i64)(NSEG + 1) * 4;
    int* cursor = (int*)(ws + off);     off += (i64)NSEG * 4;
    int* bsum   = (int*)(ws + off);     off += 512 * 4;
    int* gcur   = (int*)(ws + off);     off += NBKT * 4;
    int* esrc4  = (int*)(ws + off);     off += (i64)total * 4;

    const int NB = (NSEG + 1023) / 1024;

    // ---- CSR build ----
    hipMemsetAsync(cnt, 0, (size_t)NSEG * 4, stream);
    k_cvt_bf16<<<(NU * 32 + 255) / 256, 256, 0, stream>>>(h_user, hu2, NU * 32);
    k_hist3<<<(total + 255) / 256, 256, 0, stream>>>(
        pub_dst, n_pub, com_dst, n_com, ucu_dst, n_ucu, cnt);
    k_scan_block<<<NB, 1024, 0, stream>>>(cnt, NSEG, rptr, bsum);
    k_scan_bsum<<<1, 512, 0, stream>>>(bsum, NB);
    k_scan_add<<<NB, 1024, 0, stream>>>(rptr, NSEG, bsum, cursor, gcur, total);
    k_bucketA<<<(total + TILE_A - 1) / TILE_A, 256, 0, stream>>>(
        pub_src, pub_dst, n_pub, com_src, com_dst, n_com,
        ucu_src, ucu_dst, n_ucu, gcur, recsA, total);
    k_fillB<<<(total + 255) / 256, 256, 0, stream>>>(
        recsA, total, n_pub, cursor, esrc4, rec8);

    // ---- z = relu(LN(concat(h_user,user_ctx) @ W_conv + b_conv)) -> bf16 zbuf ----
    // (after fillB: zbuf overlays recsA)
    k_zgemm_ln<<<NU / 32, 256, 0, stream>>>(
        h_user, user_ctx, W_conv, b_conv, ln_g, ln_b, zbuf);

    // ---- gathers ----
    k_gather_com<<<NP * 64 / 256, 256, 0, stream>>>(
        hu2, e_com, rptr + NP, rec8, n_pub, NP, out1, accE);
    k_gather128b<<<NU * 64 / 256, 256, 0, stream>>>(
        zbuf, rptr + 2 * NP, esrc4, NU, out2, 1);
    k_gather128b<<<NP * 64 / 256, 256, 0, stream>>>(
        hu2, rptr, esrc4, NP, out0, 0);

    // ---- final relation GEMMs (in place on out planes) ----
    k_rowgemm<<<NP / 32, 256, 0, stream>>>(
        out0, 128, W_pub, nullptr, 0, nullptr,
        1.f, 1.f, b_pub, 1.f, nullptr, 0.f, rptr, out0);
    k_rowgemm<<<NP / 32, 256, 0, stream>>>(
        out1, 128, W_com, accE, 64, W_ecom,
        0.7f / 0.3f, 0.3f, b_com, 0.7f, b_ecom, 0.3f, rptr + NP, out1);
}

// Round 5
// 803.481 us; speedup vs baseline: 9.4024x; 1.2284x over previous
//
#include <hip/hip_runtime.h>

typedef long long i64;
typedef unsigned int uint;
typedef unsigned long long u64;
typedef __attribute__((ext_vector_type(8))) short bf16x8;
typedef __attribute__((ext_vector_type(4))) float f32x4;

#define NU 100000
#define NP 100000
#define NSEG 300000   // pub dst' [0,NP), com [NP,2NP), ucu [2NP,2NP+NU)
#define LBKT 11
#define NBKT 160      // ceil(300000/2048)=147 used

// ---------------- bf16 helpers ----------------
__device__ __forceinline__ uint f2b2(float x, float y) {
    uint ux = __float_as_uint(x), uy = __float_as_uint(y);
    ux = (ux + 0x7FFFu + ((ux >> 16) & 1u)) >> 16;
    uy = (uy + 0x7FFFu + ((uy >> 16) & 1u)) >> 16;
    return ux | (uy << 16);
}
__device__ __forceinline__ float blo(uint a) { return __uint_as_float(a << 16); }
__device__ __forceinline__ float bhi(uint a) { return __uint_as_float(a & 0xFFFF0000u); }

// ---------------- CSR build ----------------
__global__ __launch_bounds__(256) void k_hist3(
    const int* __restrict__ d0, int n0, const int* __restrict__ d1, int n1,
    const int* __restrict__ d2, int n2, int* __restrict__ cnt)
{
    int e = blockIdx.x * 256 + threadIdx.x;
    if (e < n0) { atomicAdd(cnt + d0[e], 1); return; }
    e -= n0;
    if (e < n1) { atomicAdd(cnt + NP + d1[e], 1); return; }
    e -= n1;
    if (e < n2) atomicAdd(cnt + 2 * NP + d2[e], 1);
}

__global__ __launch_bounds__(1024) void k_scan_block(
    const int* __restrict__ in, int n, int* __restrict__ out, int* __restrict__ bsum)
{
    __shared__ int sm[1024];
    int gid = blockIdx.x * 1024 + threadIdx.x;
    int v = (gid < n) ? in[gid] : 0;
    sm[threadIdx.x] = v;
    __syncthreads();
    for (int off = 1; off < 1024; off <<= 1) {
        int t = (threadIdx.x >= (unsigned)off) ? sm[threadIdx.x - off] : 0;
        __syncthreads();
        sm[threadIdx.x] += t;
        __syncthreads();
    }
    if (gid < n) out[gid] = sm[threadIdx.x] - v;      // exclusive
    if (threadIdx.x == 1023) bsum[blockIdx.x] = sm[1023];
}

__global__ __launch_bounds__(512) void k_scan_bsum(int* __restrict__ bsum, int nb)
{
    __shared__ int sm[512];
    int v = (threadIdx.x < (unsigned)nb) ? bsum[threadIdx.x] : 0;
    sm[threadIdx.x] = v;
    __syncthreads();
    for (int off = 1; off < 512; off <<= 1) {
        int t = (threadIdx.x >= (unsigned)off) ? sm[threadIdx.x - off] : 0;
        __syncthreads();
        sm[threadIdx.x] += t;
        __syncthreads();
    }
    if (threadIdx.x < (unsigned)nb) bsum[threadIdx.x] = sm[threadIdx.x] - v;  // exclusive
}

__global__ __launch_bounds__(1024) void k_scan_add(
    int* __restrict__ rptr, int n, const int* __restrict__ bsum,
    int* __restrict__ cursor, int* __restrict__ gcur, int total)
{
    int gid = blockIdx.x * 1024 + threadIdx.x;
    if (gid < n) {
        int v = rptr[gid] + bsum[blockIdx.x];
        rptr[gid] = v;
        cursor[gid] = v;
        if ((gid & 2047) == 0) gcur[gid >> LBKT] = v;  // bucket base cursors
    }
    if (gid == 0) rptr[n] = total;
}

// pass A: bucket records (src|dst'<<17|eid<<36) into 2048-dst buckets
#define TILE_A 4096
__global__ __launch_bounds__(256) void k_bucketA(
    const int* __restrict__ ps, const int* __restrict__ pd, int n0,
    const int* __restrict__ cs, const int* __restrict__ cd, int n1,
    const int* __restrict__ us, const int* __restrict__ ud, int n2,
    int* __restrict__ gcur, u64* __restrict__ recs, int total)
{
    __shared__ int hist[NBKT];
    __shared__ int base[NBKT];
    int t0 = blockIdx.x * TILE_A;
    for (int i = threadIdx.x; i < NBKT; i += 256) hist[i] = 0;
    __syncthreads();
    u64 rec[16];
    int bkt[16];
#pragma unroll
    for (int i = 0; i < 16; ++i) {
        int e = t0 + i * 256 + threadIdx.x;
        if (e < total) {
            int src, dp, eid;
            if (e < n0) { src = ps[e]; dp = pd[e]; eid = 0; }
            else if (e < n0 + n1) { int le = e - n0; src = cs[le]; dp = NP + cd[le]; eid = le; }
            else { int le = e - n0 - n1; src = us[le]; dp = 2 * NP + ud[le]; eid = 0; }
            rec[i] = (u64)src | ((u64)dp << 17) | ((u64)eid << 36);
            bkt[i] = dp >> LBKT;
            atomicAdd(&hist[bkt[i]], 1);
        } else bkt[i] = -1;
    }
    __syncthreads();
    for (int i = threadIdx.x; i < NBKT; i += 256) {
        int h = hist[i];
        base[i] = h ? atomicAdd(gcur + i, h) : 0;
    }
    __syncthreads();
    for (int i = threadIdx.x; i < NBKT; i += 256) hist[i] = 0;
    __syncthreads();
#pragma unroll
    for (int i = 0; i < 16; ++i) {
        if (bkt[i] >= 0) {
            int r = atomicAdd(&hist[bkt[i]], 1);
            recs[(i64)base[bkt[i]] + r] = rec[i];
        }
    }
}

// pass B: exact per-dst scatter, bucket-localized writes/atomics
__global__ __launch_bounds__(256) void k_fillB(
    const u64* __restrict__ recs, int total, int n0,
    int* __restrict__ cursor, int* __restrict__ esrc4, u64* __restrict__ rec8)
{
    int p = blockIdx.x * 256 + threadIdx.x;
    if (p >= total) return;
    u64 rec = recs[p];
    int src = (int)(rec & 0x1FFFF);
    int dp  = (int)((rec >> 17) & 0x7FFFF);
    int eid = (int)(rec >> 36);
    int q = atomicAdd(cursor + dp, 1);
    if (dp >= NP && dp < 2 * NP) rec8[q - n0] = (u64)(uint)src | ((u64)(uint)eid << 32);
    else esrc4[q] = src;
}

// ---------------- CSR gathers (bf16 tables), one wave per row, 8-wide ----------------
// outb != null -> write bf16 sums; else f32 (optional divide)
__global__ __launch_bounds__(256) void k_gather128b(
    const uint* __restrict__ feat, const int* __restrict__ rp,
    const int* __restrict__ esrc, int nrow,
    float* __restrict__ outf, uint* __restrict__ outb, int divide)
{
    int t = blockIdx.x * 256 + threadIdx.x;
    int row = t >> 6;
    if (row >= nrow) return;
    int lane = t & 63;
    int beg = rp[row], end = rp[row + 1];
    float ax = 0.f, ay = 0.f;
    int j = beg;
    for (; j + 8 <= end; j += 8) {
        int s[8];
#pragma unroll
        for (int k = 0; k < 8; ++k) s[k] = esrc[j + k];
        uint a[8];
#pragma unroll
        for (int k = 0; k < 8; ++k) a[k] = feat[(i64)s[k] * 64 + lane];
#pragma unroll
        for (int k = 0; k < 8; ++k) { ax += blo(a[k]); ay += bhi(a[k]); }
    }
    if (j < end) {
        int rem = end - j;
        int s[8]; uint a[8];
#pragma unroll
        for (int k = 0; k < 8; ++k) s[k] = esrc[min(j + k, end - 1)];
#pragma unroll
        for (int k = 0; k < 8; ++k) a[k] = feat[(i64)s[k] * 64 + lane];
#pragma unroll
        for (int k = 0; k < 8; ++k) {
            float m = (k < rem) ? 1.f : 0.f;
            ax = fmaf(m, blo(a[k]), ax); ay = fmaf(m, bhi(a[k]), ay);
        }
    }
    if (outb) {
        outb[(i64)row * 64 + lane] = f2b2(ax, ay);
        return;
    }
    if (divide) {
        int deg = end - beg;
        float mm = deg > 0 ? 1.f / (float)deg : 0.f;
        ax *= mm; ay *= mm;
    }
    float2 o; o.x = ax; o.y = ay;
    *(float2*)(outf + (i64)row * 128 + lane * 2) = o;
}

__global__ __launch_bounds__(256) void k_gather_com(
    const uint* __restrict__ hu2, const float* __restrict__ ec,
    const int* __restrict__ rp, const u64* __restrict__ rec8, int ebase, int nrow,
    uint* __restrict__ outUb, uint* __restrict__ outEb)
{
    int t = blockIdx.x * 256 + threadIdx.x;
    int row = t >> 6;
    if (row >= nrow) return;
    int lane = t & 63;
    int beg = rp[row], end = rp[row + 1];
    float ax = 0.f, ay = 0.f, aE = 0.f;
    int j = beg;
    for (; j + 8 <= end; j += 8) {
        u64 r[8];
#pragma unroll
        for (int k = 0; k < 8; ++k) r[k] = rec8[j + k - ebase];
        uint a[8]; float f[8];
#pragma unroll
        for (int k = 0; k < 8; ++k) {
            int s = (int)(uint)r[k];
            int e = (int)(r[k] >> 32);
            a[k] = hu2[(i64)s * 64 + lane];
            f[k] = ec[(i64)e * 64 + lane];
        }
#pragma unroll
        for (int k = 0; k < 8; ++k) { ax += blo(a[k]); ay += bhi(a[k]); aE += f[k]; }
    }
    if (j < end) {
        int rem = end - j;
        u64 r[8];
#pragma unroll
        for (int k = 0; k < 8; ++k) r[k] = rec8[min(j + k, end - 1) - ebase];
        uint a[8]; float f[8];
#pragma unroll
        for (int k = 0; k < 8; ++k) {
            int s = (int)(uint)r[k];
            int e = (int)(r[k] >> 32);
            a[k] = hu2[(i64)s * 64 + lane];
            f[k] = ec[(i64)e * 64 + lane];
        }
#pragma unroll
        for (int k = 0; k < 8; ++k) {
            float m = (k < rem) ? 1.f : 0.f;
            ax = fmaf(m, blo(a[k]), ax); ay = fmaf(m, bhi(a[k]), ay);
            aE = fmaf(m, f[k], aE);
        }
    }
    outUb[(i64)row * 64 + lane] = f2b2(ax, ay);
    // pack accE pairs: even lane stores (feat lane, feat lane+1)
    float aE2 = __shfl_xor(aE, 1);
    if (!(lane & 1)) outEb[(i64)row * 32 + (lane >> 1)] = f2b2(aE, aE2);
}

// ---------------- z-GEMM fused with LayerNorm+ReLU, bf16 out; also emits hu2 ----------------
__global__ __launch_bounds__(256) void k_zgemm_ln(
    const float* __restrict__ hu, const float* __restrict__ ctx,
    const float* __restrict__ W, const float* __restrict__ bias,
    const float* __restrict__ ln_g, const float* __restrict__ ln_b,
    uint* __restrict__ zout, uint* __restrict__ hu2out)
{
    const int fg = threadIdx.x & 31;
    const int ug = threadIdx.x >> 5;
    const int u0 = blockIdx.x * 32 + ug * 4;

    float acc[4][4];
#pragma unroll
    for (int i = 0; i < 4; ++i)
#pragma unroll
        for (int q = 0; q < 4; ++q) acc[i][q] = 0.f;

    {
        const float* xr0 = hu + (i64)(u0 + 0) * 128;
        const float* xr1 = hu + (i64)(u0 + 1) * 128;
        const float* xr2 = hu + (i64)(u0 + 2) * 128;
        const float* xr3 = hu + (i64)(u0 + 3) * 128;
        for (int k = 0; k < 128; k += 4) {
            float xa[4], xb[4], xc[4], xd[4];
            *(float4*)xa = *(const float4*)(xr0 + k);
            *(float4*)xb = *(const float4*)(xr1 + k);
            *(float4*)xc = *(const float4*)(xr2 + k);
            *(float4*)xd = *(const float4*)(xr3 + k);
            if ((k >> 2) == fg) {   // emit bf16 copy of h_user (this fg owns cols k..k+3)
                uint2 p;
                p.x = f2b2(xa[0], xa[1]); p.y = f2b2(xa[2], xa[3]);
                *(uint2*)(hu2out + (i64)(u0 + 0) * 64 + fg * 2) = p;
                p.x = f2b2(xb[0], xb[1]); p.y = f2b2(xb[2], xb[3]);
                *(uint2*)(hu2out + (i64)(u0 + 1) * 64 + fg * 2) = p;
                p.x = f2b2(xc[0], xc[1]); p.y = f2b2(xc[2], xc[3]);
                *(uint2*)(hu2out + (i64)(u0 + 2) * 64 + fg * 2) = p;
                p.x = f2b2(xd[0], xd[1]); p.y = f2b2(xd[2], xd[3]);
                *(uint2*)(hu2out + (i64)(u0 + 3) * 64 + fg * 2) = p;
            }
#pragma unroll
            for (int jj = 0; jj < 4; ++jj) {
                float w[4];
                *(float4*)w = *(const float4*)(W + (i64)(k + jj) * 128 + fg * 4);
#pragma unroll
                for (int q = 0; q < 4; ++q) {
                    acc[0][q] = fmaf(xa[jj], w[q], acc[0][q]);
                    acc[1][q] = fmaf(xb[jj], w[q], acc[1][q]);
                    acc[2][q] = fmaf(xc[jj], w[q], acc[2][q]);
                    acc[3][q] = fmaf(xd[jj], w[q], acc[3][q]);
                }
            }
        }
    }
    {
        const float* xr0 = ctx + (i64)(u0 + 0) * 64;
        const float* xr1 = ctx + (i64)(u0 + 1) * 64;
        const float* xr2 = ctx + (i64)(u0 + 2) * 64;
        const float* xr3 = ctx + (i64)(u0 + 3) * 64;
        const float* W2 = W + (i64)128 * 128;
        for (int k = 0; k < 64; k += 4) {
            float xa[4], xb[4], xc[4], xd[4];
            *(float4*)xa = *(const float4*)(xr0 + k);
            *(float4*)xb = *(const float4*)(xr1 + k);
            *(float4*)xc = *(const float4*)(xr2 + k);
            *(float4*)xd = *(const float4*)(xr3 + k);
#pragma unroll
            for (int jj = 0; jj < 4; ++jj) {
                float w[4];
                *(float4*)w = *(const float4*)(W2 + (i64)(k + jj) * 128 + fg * 4);
#pragma unroll
                for (int q = 0; q < 4; ++q) {
                    acc[0][q] = fmaf(xa[jj], w[q], acc[0][q]);
                    acc[1][q] = fmaf(xb[jj], w[q], acc[1][q]);
                    acc[2][q] = fmaf(xc[jj], w[q], acc[2][q]);
                    acc[3][q] = fmaf(xd[jj], w[q], acc[3][q]);
                }
            }
        }
    }

    float bv[4], gg[4], bb[4];
    *(float4*)bv = *(const float4*)(bias + fg * 4);
    *(float4*)gg = *(const float4*)(ln_g + fg * 4);
    *(float4*)bb = *(const float4*)(ln_b + fg * 4);

#pragma unroll
    for (int i = 0; i < 4; ++i) {
        float v[4];
#pragma unroll
        for (int q = 0; q < 4; ++q) v[q] = acc[i][q] + bv[q];
        float s = (v[0] + v[1]) + (v[2] + v[3]);
#pragma unroll
        for (int m = 1; m < 32; m <<= 1) s += __shfl_xor(s, m, 32);
        float mu = s * (1.f / 128.f);
        float d[4];
#pragma unroll
        for (int q = 0; q < 4; ++q) d[q] = v[q] - mu;
        float sq = (d[0] * d[0] + d[1] * d[1]) + (d[2] * d[2] + d[3] * d[3]);
#pragma unroll
        for (int m = 1; m < 32; m <<= 1) sq += __shfl_xor(sq, m, 32);
        float rs = rsqrtf(sq * (1.f / 128.f) + 1e-5f);
        float o[4];
#pragma unroll
        for (int q = 0; q < 4; ++q) o[q] = fmaxf(0.f, d[q] * rs * gg[q] + bb[q]);
        uint2 z2; z2.x = f2b2(o[0], o[1]); z2.y = f2b2(o[2], o[3]);
        *(uint2*)(zout + (i64)(u0 + i) * 64 + fg * 2) = z2;
    }
}

// ---------------- weight prepack into MFMA B-fragment layout (bf16, scaled) -----
// dst[((kt+ktoff)*8+ct)*64 + lane] : 8 bf16 = B[k = kt*32 + (lane>>4)*8 + jj][ct*16 + (lane&15)]
__global__ __launch_bounds__(256) void k_prepack(
    const float* __restrict__ W, int ktiles, int ktoff, float scale,
    uint4* __restrict__ dst)
{
    int t = blockIdx.x * 256 + threadIdx.x;
    if (t >= ktiles * 8 * 64) return;
    int lane = t & 63, ctkt = t >> 6;
    int kt = ctkt >> 3, ct = ctkt & 7;
    int r = lane & 15, g = lane >> 4;
    float v[8];
#pragma unroll
    for (int jj = 0; jj < 8; ++jj)
        v[jj] = W[(i64)(kt * 32 + g * 8 + jj) * 128 + ct * 16 + r] * scale;
    uint4 o;
    o.x = f2b2(v[0], v[1]); o.y = f2b2(v[2], v[3]);
    o.z = f2b2(v[4], v[5]); o.w = f2b2(v[6], v[7]);
    dst[((kt + ktoff) * 8 + ct) * 64 + lane] = o;
}

// ---------------- MFMA rowwise GEMM: out = (Xu@W0 + Xe@W1)/deg + bias ----------------
// Xu: [nrow][nktU*16] uints (bf16 pairs); Xe optional. 4 waves/block, 16 rows/wave.
__global__ __launch_bounds__(256) void k_mfma_rowgemm(
    const uint* __restrict__ Xu, const uint* __restrict__ Xe,
    int nktU, int nktE, const uint4* __restrict__ Wp,
    const float* __restrict__ b0, float bs0,
    const float* __restrict__ b1, float bs1,
    const int* __restrict__ rp, float* __restrict__ out, int nrow)
{
    const int wave = threadIdx.x >> 6;
    const int lane = threadIdx.x & 63;
    const int row0 = blockIdx.x * 64 + wave * 16;
    const int r = lane & 15, g = lane >> 4;
    const int arow = min(row0 + r, nrow - 1);
    const bf16x8* wp = (const bf16x8*)Wp;

    f32x4 acc[8];
#pragma unroll
    for (int ct = 0; ct < 8; ++ct) acc[ct] = (f32x4){0.f, 0.f, 0.f, 0.f};

    const int ldu = nktU * 16;
    const uint* xu = Xu + (i64)arow * ldu + g * 4;
    for (int kt = 0; kt < nktU; ++kt) {
        bf16x8 a = *(const bf16x8*)(xu + kt * 16);
#pragma unroll
        for (int ct = 0; ct < 8; ++ct)
            acc[ct] = __builtin_amdgcn_mfma_f32_16x16x32_bf16(
                a, wp[(kt * 8 + ct) * 64 + lane], acc[ct], 0, 0, 0);
    }
    if (nktE) {
        const int lde = nktE * 16;
        const uint* xe = Xe + (i64)arow * lde + g * 4;
        for (int kt = 0; kt < nktE; ++kt) {
            bf16x8 a = *(const bf16x8*)(xe + kt * 16);
#pragma unroll
            for (int ct = 0; ct < 8; ++ct)
                acc[ct] = __builtin_amdgcn_mfma_f32_16x16x32_bf16(
                    a, wp[((nktU + kt) * 8 + ct) * 64 + lane], acc[ct], 0, 0, 0);
        }
    }

    float bv[8];
#pragma unroll
    for (int ct = 0; ct < 8; ++ct) {
        float b = bs0 * b0[ct * 16 + r];
        if (b1) b += bs1 * b1[ct * 16 + r];
        bv[ct] = b;
    }

#pragma unroll
    for (int q = 0; q < 4; ++q) {
        int orow = row0 + g * 4 + q;
        if (orow < nrow) {
            int deg = rp[orow + 1] - rp[orow];
            float m = deg > 0 ? 1.f / (float)deg : 0.f;
            float gate = deg > 0 ? 1.f : 0.f;
#pragma unroll
            for (int ct = 0; ct < 8; ++ct)
                out[(i64)orow * 128 + ct * 16 + r] = gate * fmaf(acc[ct][q], m, bv[ct]);
        }
    }
}

extern "C" void kernel_launch(void* const* d_in, const int* in_sizes, int n_in,
                              void* d_out, int out_size, void* d_ws, size_t ws_size,
                              hipStream_t stream)
{
    const float* h_user   = (const float*)d_in[0];
    const float* user_ctx = (const float*)d_in[2];
    const float* e_com    = (const float*)d_in[3];
    const int* pub_src = (const int*)d_in[4];
    const int* pub_dst = (const int*)d_in[5];
    const int* com_src = (const int*)d_in[6];
    const int* com_dst = (const int*)d_in[7];
    const int* ucu_src = (const int*)d_in[8];
    const int* ucu_dst = (const int*)d_in[9];
    const float* W_pub  = (const float*)d_in[10];
    const float* b_pub  = (const float*)d_in[11];
    const float* W_com  = (const float*)d_in[12];
    const float* b_com  = (const float*)d_in[13];
    const float* W_conv = (const float*)d_in[14];
    const float* b_conv = (const float*)d_in[15];
    const float* ln_g   = (const float*)d_in[16];
    const float* ln_b   = (const float*)d_in[17];
    const float* W_ecom = (const float*)d_in[18];
    const float* b_ecom = (const float*)d_in[19];

    const int n_pub = in_sizes[4];
    const int n_com = in_sizes[6];
    const int n_ucu = in_sizes[8];
    const int total = n_pub + n_com + n_ucu;

    float* out0 = (float*)d_out;
    float* out1 = out0 + (i64)NP * 128;
    float* out2 = out1 + (i64)NP * 128;

    // ---- ws layout (16B-aligned chunks); zbuf overlays recsA (dead after fillB) ----
    char* ws = (char*)d_ws;
    i64 off = 0;
    auto alloc = [&](i64 bytes) { i64 p = off; off += (bytes + 15) & ~15LL; return p; };
    uint* hu2   = (uint*)(ws + alloc((i64)NU * 64 * 4));
    i64 reg2_sz = (i64)total * 8 > (i64)NU * 64 * 4 ? (i64)total * 8 : (i64)NU * 64 * 4;
    i64 reg2    = alloc(reg2_sz);
    u64* recsA  = (u64*)(ws + reg2);
    uint* zbuf  = (uint*)(ws + reg2);
    uint* sumP  = (uint*)(ws + alloc((i64)NP * 64 * 4));
    uint* sumU  = (uint*)(ws + alloc((i64)NP * 64 * 4));
    uint* accEb = (uint*)(ws + alloc((i64)NP * 32 * 4));
    u64* rec8   = (u64*)(ws + alloc((i64)n_com * 8));
    int* cnt    = (int*)(ws + alloc((i64)NSEG * 4));
    int* rptr   = (int*)(ws + alloc((i64)(NSEG + 1) * 4));
    int* cursor = (int*)(ws + alloc((i64)NSEG * 4));
    int* bsum   = (int*)(ws + alloc(512 * 4));
    int* gcur   = (int*)(ws + alloc(NBKT * 4));
    int* esrc4  = (int*)(ws + alloc((i64)total * 4));
    uint4* WpkP = (uint4*)(ws + alloc(4 * 8 * 64 * 16));   // W_pub packed, K=128
    uint4* WpkC = (uint4*)(ws + alloc(6 * 8 * 64 * 16));   // [0.7*W_com ; 0.3*W_ecom], K=192

    const int NB = (NSEG + 1023) / 1024;

    // ---- weight prepack (tiny) ----
    k_prepack<<<8, 256, 0, stream>>>(W_pub, 4, 0, 1.0f, WpkP);
    k_prepack<<<8, 256, 0, stream>>>(W_com, 4, 0, 0.7f, WpkC);
    k_prepack<<<4, 256, 0, stream>>>(W_ecom, 2, 4, 0.3f, WpkC);

    // ---- CSR build ----
    hipMemsetAsync(cnt, 0, (size_t)NSEG * 4, stream);
    k_hist3<<<(total + 255) / 256, 256, 0, stream>>>(
        pub_dst, n_pub, com_dst, n_com, ucu_dst, n_ucu, cnt);
    k_scan_block<<<NB, 1024, 0, stream>>>(cnt, NSEG, rptr, bsum);
    k_scan_bsum<<<1, 512, 0, stream>>>(bsum, NB);
    k_scan_add<<<NB, 1024, 0, stream>>>(rptr, NSEG, bsum, cursor, gcur, total);
    k_bucketA<<<(total + TILE_A - 1) / TILE_A, 256, 0, stream>>>(
        pub_src, pub_dst, n_pub, com_src, com_dst, n_com,
        ucu_src, ucu_dst, n_ucu, gcur, recsA, total);
    k_fillB<<<(total + 255) / 256, 256, 0, stream>>>(
        recsA, total, n_pub, cursor, esrc4, rec8);

    // ---- z = relu(LN(...)) -> bf16 zbuf (overlays recsA); also emits hu2 bf16 ----
    k_zgemm_ln<<<NU / 32, 256, 0, stream>>>(
        h_user, user_ctx, W_conv, b_conv, ln_g, ln_b, zbuf, hu2);

    // ---- gathers ----
    k_gather_com<<<NP * 64 / 256, 256, 0, stream>>>(
        hu2, e_com, rptr + NP, rec8, n_pub, NP, sumU, accEb);
    k_gather128b<<<NU * 64 / 256, 256, 0, stream>>>(
        zbuf, rptr + 2 * NP, esrc4, NU, out2, nullptr, 1);     // user_new final
    k_gather128b<<<NP * 64 / 256, 256, 0, stream>>>(
        hu2, rptr, esrc4, NP, nullptr, sumP, 0);               // pub sums bf16

    // ---- final relation GEMMs via MFMA ----
    k_mfma_rowgemm<<<(NP + 63) / 64, 256, 0, stream>>>(
        sumP, nullptr, 4, 0, WpkP, b_pub, 1.0f, nullptr, 0.f, rptr, out0, NP);
    k_mfma_rowgemm<<<(NP + 63) / 64, 256, 0, stream>>>(
        sumU, accEb, 4, 2, WpkC, b_com, 0.7f, b_ecom, 0.3f, rptr + NP, out1, NP);
}

// Round 6
// 646.034 us; speedup vs baseline: 11.6938x; 1.2437x over previous
//
#include <hip/hip_runtime.h>

typedef long long i64;
typedef unsigned int uint;
typedef unsigned long long u64;
typedef __attribute__((ext_vector_type(8))) short bf16x8;
typedef __attribute__((ext_vector_type(4))) float f32x4;

#define NU 100000
#define NP 100000
#define NSEG 300000   // pub dst' [0,NP), com [NP,2NP), ucu [2NP,2NP+NU)
#define LBKT 11
#define NBKT 160      // ceil(300000/2048)=147 used

// ---------------- bf16 helpers ----------------
__device__ __forceinline__ uint f2b2(float x, float y) {
    uint ux = __float_as_uint(x), uy = __float_as_uint(y);
    ux = (ux + 0x7FFFu + ((ux >> 16) & 1u)) >> 16;
    uy = (uy + 0x7FFFu + ((uy >> 16) & 1u)) >> 16;
    return ux | (uy << 16);
}
__device__ __forceinline__ float blo(uint a) { return __uint_as_float(a << 16); }
__device__ __forceinline__ float bhi(uint a) { return __uint_as_float(a & 0xFFFF0000u); }

// convert h_user [NU][128] and user_ctx [NU][64] f32 -> bf16-pair tables
__global__ __launch_bounds__(256) void k_cvt2(
    const float* __restrict__ hu, const float* __restrict__ ctx,
    uint* __restrict__ hu2, uint* __restrict__ ctx2)
{
    int t = blockIdx.x * 256 + threadIdx.x;
    if (t < NU * 32) {
        float4 v = *(const float4*)(hu + (i64)t * 4);
        uint2 o; o.x = f2b2(v.x, v.y); o.y = f2b2(v.z, v.w);
        *(uint2*)(hu2 + (i64)t * 2) = o;
    } else {
        t -= NU * 32;
        if (t < NU * 16) {
            float4 v = *(const float4*)(ctx + (i64)t * 4);
            uint2 o; o.x = f2b2(v.x, v.y); o.y = f2b2(v.z, v.w);
            *(uint2*)(ctx2 + (i64)t * 2) = o;
        }
    }
}

// ---------------- CSR build ----------------
__global__ __launch_bounds__(256) void k_hist3(
    const int* __restrict__ d0, int n0, const int* __restrict__ d1, int n1,
    const int* __restrict__ d2, int n2, int* __restrict__ cnt)
{
    int e = blockIdx.x * 256 + threadIdx.x;
    if (e < n0) { atomicAdd(cnt + d0[e], 1); return; }
    e -= n0;
    if (e < n1) { atomicAdd(cnt + NP + d1[e], 1); return; }
    e -= n1;
    if (e < n2) atomicAdd(cnt + 2 * NP + d2[e], 1);
}

__global__ __launch_bounds__(1024) void k_scan_block(
    const int* __restrict__ in, int n, int* __restrict__ out, int* __restrict__ bsum)
{
    __shared__ int sm[1024];
    int gid = blockIdx.x * 1024 + threadIdx.x;
    int v = (gid < n) ? in[gid] : 0;
    sm[threadIdx.x] = v;
    __syncthreads();
    for (int off = 1; off < 1024; off <<= 1) {
        int t = (threadIdx.x >= (unsigned)off) ? sm[threadIdx.x - off] : 0;
        __syncthreads();
        sm[threadIdx.x] += t;
        __syncthreads();
    }
    if (gid < n) out[gid] = sm[threadIdx.x] - v;      // exclusive
    if (threadIdx.x == 1023) bsum[blockIdx.x] = sm[1023];
}

__global__ __launch_bounds__(512) void k_scan_bsum(int* __restrict__ bsum, int nb)
{
    __shared__ int sm[512];
    int v = (threadIdx.x < (unsigned)nb) ? bsum[threadIdx.x] : 0;
    sm[threadIdx.x] = v;
    __syncthreads();
    for (int off = 1; off < 512; off <<= 1) {
        int t = (threadIdx.x >= (unsigned)off) ? sm[threadIdx.x - off] : 0;
        __syncthreads();
        sm[threadIdx.x] += t;
        __syncthreads();
    }
    if (threadIdx.x < (unsigned)nb) bsum[threadIdx.x] = sm[threadIdx.x] - v;  // exclusive
}

__global__ __launch_bounds__(1024) void k_scan_add(
    int* __restrict__ rptr, int n, const int* __restrict__ bsum,
    int* __restrict__ cursor, int* __restrict__ gcur, int total)
{
    int gid = blockIdx.x * 1024 + threadIdx.x;
    if (gid < n) {
        int v = rptr[gid] + bsum[blockIdx.x];
        rptr[gid] = v;
        cursor[gid] = v;
        if ((gid & 2047) == 0) gcur[gid >> LBKT] = v;  // bucket base cursors
    }
    if (gid == 0) rptr[n] = total;
}

// pass A: bucket records (src|dst'<<17|eid<<36) into 2048-dst buckets
#define TILE_A 4096
__global__ __launch_bounds__(256) void k_bucketA(
    const int* __restrict__ ps, const int* __restrict__ pd, int n0,
    const int* __restrict__ cs, const int* __restrict__ cd, int n1,
    const int* __restrict__ us, const int* __restrict__ ud, int n2,
    int* __restrict__ gcur, u64* __restrict__ recs, int total)
{
    __shared__ int hist[NBKT];
    __shared__ int base[NBKT];
    int t0 = blockIdx.x * TILE_A;
    for (int i = threadIdx.x; i < NBKT; i += 256) hist[i] = 0;
    __syncthreads();
    u64 rec[16];
    int bkt[16];
#pragma unroll
    for (int i = 0; i < 16; ++i) {
        int e = t0 + i * 256 + threadIdx.x;
        if (e < total) {
            int src, dp, eid;
            if (e < n0) { src = ps[e]; dp = pd[e]; eid = 0; }
            else if (e < n0 + n1) { int le = e - n0; src = cs[le]; dp = NP + cd[le]; eid = le; }
            else { int le = e - n0 - n1; src = us[le]; dp = 2 * NP + ud[le]; eid = 0; }
            rec[i] = (u64)src | ((u64)dp << 17) | ((u64)eid << 36);
            bkt[i] = dp >> LBKT;
            atomicAdd(&hist[bkt[i]], 1);
        } else bkt[i] = -1;
    }
    __syncthreads();
    for (int i = threadIdx.x; i < NBKT; i += 256) {
        int h = hist[i];
        base[i] = h ? atomicAdd(gcur + i, h) : 0;
    }
    __syncthreads();
    for (int i = threadIdx.x; i < NBKT; i += 256) hist[i] = 0;
    __syncthreads();
#pragma unroll
    for (int i = 0; i < 16; ++i) {
        if (bkt[i] >= 0) {
            int r = atomicAdd(&hist[bkt[i]], 1);
            recs[(i64)base[bkt[i]] + r] = rec[i];
        }
    }
}

// pass B: exact per-dst scatter, bucket-localized writes/atomics
__global__ __launch_bounds__(256) void k_fillB(
    const u64* __restrict__ recs, int total, int n0,
    int* __restrict__ cursor, int* __restrict__ esrc4, u64* __restrict__ rec8)
{
    int p = blockIdx.x * 256 + threadIdx.x;
    if (p >= total) return;
    u64 rec = recs[p];
    int src = (int)(rec & 0x1FFFF);
    int dp  = (int)((rec >> 17) & 0x7FFFF);
    int eid = (int)(rec >> 36);
    int q = atomicAdd(cursor + dp, 1);
    if (dp >= NP && dp < 2 * NP) rec8[q - n0] = (u64)(uint)src | ((u64)(uint)eid << 32);
    else esrc4[q] = src;
}

// ---------------- CSR gathers (bf16 tables), one wave per row, 8-wide ----------------
__global__ __launch_bounds__(256) void k_gather128b(
    const uint* __restrict__ feat, const int* __restrict__ rp,
    const int* __restrict__ esrc, int nrow,
    float* __restrict__ outf, uint* __restrict__ outb, int divide)
{
    int t = blockIdx.x * 256 + threadIdx.x;
    int row = t >> 6;
    if (row >= nrow) return;
    int lane = t & 63;
    int beg = rp[row], end = rp[row + 1];
    float ax = 0.f, ay = 0.f;
    int j = beg;
    for (; j + 8 <= end; j += 8) {
        int s[8];
#pragma unroll
        for (int k = 0; k < 8; ++k) s[k] = esrc[j + k];
        uint a[8];
#pragma unroll
        for (int k = 0; k < 8; ++k) a[k] = feat[(i64)s[k] * 64 + lane];
#pragma unroll
        for (int k = 0; k < 8; ++k) { ax += blo(a[k]); ay += bhi(a[k]); }
    }
    if (j < end) {
        int rem = end - j;
        int s[8]; uint a[8];
#pragma unroll
        for (int k = 0; k < 8; ++k) s[k] = esrc[min(j + k, end - 1)];
#pragma unroll
        for (int k = 0; k < 8; ++k) a[k] = feat[(i64)s[k] * 64 + lane];
#pragma unroll
        for (int k = 0; k < 8; ++k) {
            float m = (k < rem) ? 1.f : 0.f;
            ax = fmaf(m, blo(a[k]), ax); ay = fmaf(m, bhi(a[k]), ay);
        }
    }
    if (outb) {
        outb[(i64)row * 64 + lane] = f2b2(ax, ay);
        return;
    }
    if (divide) {
        int deg = end - beg;
        float mm = deg > 0 ? 1.f / (float)deg : 0.f;
        ax *= mm; ay *= mm;
    }
    float2 o; o.x = ax; o.y = ay;
    *(float2*)(outf + (i64)row * 128 + lane * 2) = o;
}

__global__ __launch_bounds__(256) void k_gather_com(
    const uint* __restrict__ hu2, const float* __restrict__ ec,
    const int* __restrict__ rp, const u64* __restrict__ rec8, int ebase, int nrow,
    uint* __restrict__ outUb, uint* __restrict__ outEb)
{
    int t = blockIdx.x * 256 + threadIdx.x;
    int row = t >> 6;
    if (row >= nrow) return;
    int lane = t & 63;
    int beg = rp[row], end = rp[row + 1];
    float ax = 0.f, ay = 0.f, aE = 0.f;
    int j = beg;
    for (; j + 8 <= end; j += 8) {
        u64 r[8];
#pragma unroll
        for (int k = 0; k < 8; ++k) r[k] = rec8[j + k - ebase];
        uint a[8]; float f[8];
#pragma unroll
        for (int k = 0; k < 8; ++k) {
            int s = (int)(uint)r[k];
            int e = (int)(r[k] >> 32);
            a[k] = hu2[(i64)s * 64 + lane];
            f[k] = ec[(i64)e * 64 + lane];
        }
#pragma unroll
        for (int k = 0; k < 8; ++k) { ax += blo(a[k]); ay += bhi(a[k]); aE += f[k]; }
    }
    if (j < end) {
        int rem = end - j;
        u64 r[8];
#pragma unroll
        for (int k = 0; k < 8; ++k) r[k] = rec8[min(j + k, end - 1) - ebase];
        uint a[8]; float f[8];
#pragma unroll
        for (int k = 0; k < 8; ++k) {
            int s = (int)(uint)r[k];
            int e = (int)(r[k] >> 32);
            a[k] = hu2[(i64)s * 64 + lane];
            f[k] = ec[(i64)e * 64 + lane];
        }
#pragma unroll
        for (int k = 0; k < 8; ++k) {
            float m = (k < rem) ? 1.f : 0.f;
            ax = fmaf(m, blo(a[k]), ax); ay = fmaf(m, bhi(a[k]), ay);
            aE = fmaf(m, f[k], aE);
        }
    }
    outUb[(i64)row * 64 + lane] = f2b2(ax, ay);
    float aE2 = __shfl_xor(aE, 1);
    if (!(lane & 1)) outEb[(i64)row * 32 + (lane >> 1)] = f2b2(aE, aE2);
}

// ---------------- weight prepack into MFMA B-fragment layout (bf16, scaled) -----
// one kt (=32 k-rows x 128 cols) per 512 threads (2 blocks); 16 global kts.
__global__ __launch_bounds__(256) void k_prepack_all(
    const float* __restrict__ W_pub, const float* __restrict__ W_com,
    const float* __restrict__ W_ecom, const float* __restrict__ W_conv,
    uint4* __restrict__ WpkP, uint4* __restrict__ WpkC, uint4* __restrict__ WpkZ)
{
    int gkt = blockIdx.x >> 1;
    int sub = (blockIdx.x & 1) * 256 + threadIdx.x;   // 0..511 = ct*64+lane
    int lane = sub & 63, ct = sub >> 6;
    int r = lane & 15, g = lane >> 4;
    const float* W; uint4* dst; int skt, dkt; float scale;
    if (gkt < 4)       { W = W_pub;              dst = WpkP; skt = gkt;      dkt = skt;     scale = 1.0f; }
    else if (gkt < 8)  { W = W_com;              dst = WpkC; skt = gkt - 4;  dkt = skt;     scale = 0.7f; }
    else if (gkt < 10) { W = W_ecom;             dst = WpkC; skt = gkt - 8;  dkt = skt + 4; scale = 0.3f; }
    else if (gkt < 14) { W = W_conv;             dst = WpkZ; skt = gkt - 10; dkt = skt;     scale = 1.0f; }
    else               { W = W_conv + 128 * 128; dst = WpkZ; skt = gkt - 14; dkt = skt + 4; scale = 1.0f; }
    float v[8];
#pragma unroll
    for (int jj = 0; jj < 8; ++jj)
        v[jj] = W[(i64)(skt * 32 + g * 8 + jj) * 128 + ct * 16 + r] * scale;
    uint4 o;
    o.x = f2b2(v[0], v[1]); o.y = f2b2(v[2], v[3]);
    o.z = f2b2(v[4], v[5]); o.w = f2b2(v[6], v[7]);
    dst[(dkt * 8 + ct) * 64 + lane] = o;
}

// ---------------- MFMA z-GEMM (K=192) + fused LayerNorm + ReLU -> bf16 zbuf ------
__global__ __launch_bounds__(256) void k_mfma_zgemm_ln(
    const uint* __restrict__ hu2, const uint* __restrict__ ctx2,
    const uint4* __restrict__ Wp, const float* __restrict__ bias,
    const float* __restrict__ ln_g, const float* __restrict__ ln_b,
    uint* __restrict__ zout)
{
    const int wave = threadIdx.x >> 6;
    const int lane = threadIdx.x & 63;
    const int row0 = blockIdx.x * 64 + wave * 16;
    const int r = lane & 15, g = lane >> 4;
    const int arow = min(row0 + r, NU - 1);
    const bf16x8* wp = (const bf16x8*)Wp;

    f32x4 acc[8];
#pragma unroll
    for (int ct = 0; ct < 8; ++ct) acc[ct] = (f32x4){0.f, 0.f, 0.f, 0.f};

    const uint* xu = hu2 + (i64)arow * 64 + g * 4;
#pragma unroll
    for (int kt = 0; kt < 4; ++kt) {
        bf16x8 a = *(const bf16x8*)(xu + kt * 16);
#pragma unroll
        for (int ct = 0; ct < 8; ++ct)
            acc[ct] = __builtin_amdgcn_mfma_f32_16x16x32_bf16(
                a, wp[(kt * 8 + ct) * 64 + lane], acc[ct], 0, 0, 0);
    }
    const uint* xe = ctx2 + (i64)arow * 32 + g * 4;
#pragma unroll
    for (int kt = 0; kt < 2; ++kt) {
        bf16x8 a = *(const bf16x8*)(xe + kt * 16);
#pragma unroll
        for (int ct = 0; ct < 8; ++ct)
            acc[ct] = __builtin_amdgcn_mfma_f32_16x16x32_bf16(
                a, wp[((4 + kt) * 8 + ct) * 64 + lane], acc[ct], 0, 0, 0);
    }

    float bv[8], gv[8], bbv[8];
#pragma unroll
    for (int ct = 0; ct < 8; ++ct) {
        bv[ct] = bias[ct * 16 + r];
        gv[ct] = ln_g[ct * 16 + r];
        bbv[ct] = ln_b[ct * 16 + r];
    }

#pragma unroll
    for (int q = 0; q < 4; ++q) {
        int orow = row0 + g * 4 + q;
        float v[8], s = 0.f;
#pragma unroll
        for (int ct = 0; ct < 8; ++ct) { v[ct] = acc[ct][q] + bv[ct]; s += v[ct]; }
#pragma unroll
        for (int m = 1; m < 16; m <<= 1) s += __shfl_xor(s, m);
        float mu = s * (1.f / 128.f);
        float sq = 0.f;
#pragma unroll
        for (int ct = 0; ct < 8; ++ct) { float d = v[ct] - mu; sq += d * d; }
#pragma unroll
        for (int m = 1; m < 16; m <<= 1) sq += __shfl_xor(sq, m);
        float rs = rsqrtf(sq * (1.f / 128.f) + 1e-5f);
        float o[8];
#pragma unroll
        for (int ct = 0; ct < 8; ++ct)
            o[ct] = fmaxf(0.f, (v[ct] - mu) * rs * gv[ct] + bbv[ct]);
        // pack bf16 pairs across neighboring r lanes (col, col+1)
#pragma unroll
        for (int ct = 0; ct < 8; ++ct) {
            float p = __shfl_xor(o[ct], 1);
            if (!(r & 1) && orow < NU)
                zout[(i64)orow * 64 + ct * 8 + (r >> 1)] = f2b2(o[ct], p);
        }
    }
}

// ---------------- MFMA rowwise GEMM: out = (Xu@W0 + Xe@W1)/deg + bias ----------------
__global__ __launch_bounds__(256) void k_mfma_rowgemm(
    const uint* __restrict__ Xu, const uint* __restrict__ Xe,
    int nktU, int nktE, const uint4* __restrict__ Wp,
    const float* __restrict__ b0, float bs0,
    const float* __restrict__ b1, float bs1,
    const int* __restrict__ rp, float* __restrict__ out, int nrow)
{
    const int wave = threadIdx.x >> 6;
    const int lane = threadIdx.x & 63;
    const int row0 = blockIdx.x * 64 + wave * 16;
    const int r = lane & 15, g = lane >> 4;
    const int arow = min(row0 + r, nrow - 1);
    const bf16x8* wp = (const bf16x8*)Wp;

    f32x4 acc[8];
#pragma unroll
    for (int ct = 0; ct < 8; ++ct) acc[ct] = (f32x4){0.f, 0.f, 0.f, 0.f};

    const int ldu = nktU * 16;
    const uint* xu = Xu + (i64)arow * ldu + g * 4;
    for (int kt = 0; kt < nktU; ++kt) {
        bf16x8 a = *(const bf16x8*)(xu + kt * 16);
#pragma unroll
        for (int ct = 0; ct < 8; ++ct)
            acc[ct] = __builtin_amdgcn_mfma_f32_16x16x32_bf16(
                a, wp[(kt * 8 + ct) * 64 + lane], acc[ct], 0, 0, 0);
    }
    if (nktE) {
        const int lde = nktE * 16;
        const uint* xe = Xe + (i64)arow * lde + g * 4;
        for (int kt = 0; kt < nktE; ++kt) {
            bf16x8 a = *(const bf16x8*)(xe + kt * 16);
#pragma unroll
            for (int ct = 0; ct < 8; ++ct)
                acc[ct] = __builtin_amdgcn_mfma_f32_16x16x32_bf16(
                    a, wp[((nktU + kt) * 8 + ct) * 64 + lane], acc[ct], 0, 0, 0);
        }
    }

    float bv[8];
#pragma unroll
    for (int ct = 0; ct < 8; ++ct) {
        float b = bs0 * b0[ct * 16 + r];
        if (b1) b += bs1 * b1[ct * 16 + r];
        bv[ct] = b;
    }

#pragma unroll
    for (int q = 0; q < 4; ++q) {
        int orow = row0 + g * 4 + q;
        if (orow < nrow) {
            int deg = rp[orow + 1] - rp[orow];
            float m = deg > 0 ? 1.f / (float)deg : 0.f;
            float gate = deg > 0 ? 1.f : 0.f;
#pragma unroll
            for (int ct = 0; ct < 8; ++ct)
                out[(i64)orow * 128 + ct * 16 + r] = gate * fmaf(acc[ct][q], m, bv[ct]);
        }
    }
}

extern "C" void kernel_launch(void* const* d_in, const int* in_sizes, int n_in,
                              void* d_out, int out_size, void* d_ws, size_t ws_size,
                              hipStream_t stream)
{
    const float* h_user   = (const float*)d_in[0];
    const float* user_ctx = (const float*)d_in[2];
    const float* e_com    = (const float*)d_in[3];
    const int* pub_src = (const int*)d_in[4];
    const int* pub_dst = (const int*)d_in[5];
    const int* com_src = (const int*)d_in[6];
    const int* com_dst = (const int*)d_in[7];
    const int* ucu_src = (const int*)d_in[8];
    const int* ucu_dst = (const int*)d_in[9];
    const float* W_pub  = (const float*)d_in[10];
    const float* b_pub  = (const float*)d_in[11];
    const float* W_com  = (const float*)d_in[12];
    const float* b_com  = (const float*)d_in[13];
    const float* W_conv = (const float*)d_in[14];
    const float* b_conv = (const float*)d_in[15];
    const float* ln_g   = (const float*)d_in[16];
    const float* ln_b   = (const float*)d_in[17];
    const float* W_ecom = (const float*)d_in[18];
    const float* b_ecom = (const float*)d_in[19];

    const int n_pub = in_sizes[4];
    const int n_com = in_sizes[6];
    const int n_ucu = in_sizes[8];
    const int total = n_pub + n_com + n_ucu;

    float* out0 = (float*)d_out;
    float* out1 = out0 + (i64)NP * 128;
    float* out2 = out1 + (i64)NP * 128;

    // ---- ws layout; zbuf overlays recsA (recsA dead after fillB) ----
    char* ws = (char*)d_ws;
    i64 off = 0;
    auto alloc = [&](i64 bytes) { i64 p = off; off += (bytes + 15) & ~15LL; return p; };
    uint* hu2   = (uint*)(ws + alloc((i64)NU * 64 * 4));
    uint* ctx2  = (uint*)(ws + alloc((i64)NU * 32 * 4));
    i64 reg2_sz = (i64)total * 8 > (i64)NU * 64 * 4 ? (i64)total * 8 : (i64)NU * 64 * 4;
    i64 reg2    = alloc(reg2_sz);
    u64* recsA  = (u64*)(ws + reg2);
    uint* zbuf  = (uint*)(ws + reg2);
    uint* sumP  = (uint*)(ws + alloc((i64)NP * 64 * 4));
    uint* sumU  = (uint*)(ws + alloc((i64)NP * 64 * 4));
    uint* accEb = (uint*)(ws + alloc((i64)NP * 32 * 4));
    u64* rec8   = (u64*)(ws + alloc((i64)n_com * 8));
    int* cnt    = (int*)(ws + alloc((i64)NSEG * 4));
    int* rptr   = (int*)(ws + alloc((i64)(NSEG + 1) * 4));
    int* cursor = (int*)(ws + alloc((i64)NSEG * 4));
    int* bsum   = (int*)(ws + alloc(512 * 4));
    int* gcur   = (int*)(ws + alloc(NBKT * 4));
    int* esrc4  = (int*)(ws + alloc((i64)total * 4));
    uint4* WpkP = (uint4*)(ws + alloc(4 * 8 * 64 * 16));   // W_pub, K=128
    uint4* WpkC = (uint4*)(ws + alloc(6 * 8 * 64 * 16));   // [0.7*W_com ; 0.3*W_ecom], K=192
    uint4* WpkZ = (uint4*)(ws + alloc(6 * 8 * 64 * 16));   // W_conv, K=192

    const int NB = (NSEG + 1023) / 1024;

    // ---- prepack all weights (one launch) ----
    k_prepack_all<<<32, 256, 0, stream>>>(
        W_pub, W_com, W_ecom, W_conv, WpkP, WpkC, WpkZ);

    // ---- bf16 conversions ----
    k_cvt2<<<(NU * 48 + 255) / 256, 256, 0, stream>>>(h_user, user_ctx, hu2, ctx2);

    // ---- CSR build ----
    hipMemsetAsync(cnt, 0, (size_t)NSEG * 4, stream);
    k_hist3<<<(total + 255) / 256, 256, 0, stream>>>(
        pub_dst, n_pub, com_dst, n_com, ucu_dst, n_ucu, cnt);
    k_scan_block<<<NB, 1024, 0, stream>>>(cnt, NSEG, rptr, bsum);
    k_scan_bsum<<<1, 512, 0, stream>>>(bsum, NB);
    k_scan_add<<<NB, 1024, 0, stream>>>(rptr, NSEG, bsum, cursor, gcur, total);
    k_bucketA<<<(total + TILE_A - 1) / TILE_A, 256, 0, stream>>>(
        pub_src, pub_dst, n_pub, com_src, com_dst, n_com,
        ucu_src, ucu_dst, n_ucu, gcur, recsA, total);
    k_fillB<<<(total + 255) / 256, 256, 0, stream>>>(
        recsA, total, n_pub, cursor, esrc4, rec8);

    // ---- z = relu(LN(concat(hu,ctx) @ W_conv + b)) via MFMA -> bf16 zbuf ----
    // (zbuf overlays recsA, so this must follow fillB)
    k_mfma_zgemm_ln<<<(NU + 63) / 64, 256, 0, stream>>>(
        hu2, ctx2, WpkZ, b_conv, ln_g, ln_b, zbuf);

    // ---- gathers ----
    k_gather_com<<<NP * 64 / 256, 256, 0, stream>>>(
        hu2, e_com, rptr + NP, rec8, n_pub, NP, sumU, accEb);
    k_gather128b<<<NU * 64 / 256, 256, 0, stream>>>(
        zbuf, rptr + 2 * NP, esrc4, NU, out2, nullptr, 1);     // user_new final
    k_gather128b<<<NP * 64 / 256, 256, 0, stream>>>(
        hu2, rptr, esrc4, NP, nullptr, sumP, 0);               // pub sums bf16

    // ---- final relation GEMMs via MFMA ----
    k_mfma_rowgemm<<<(NP + 63) / 64, 256, 0, stream>>>(
        sumP, nullptr, 4, 0, WpkP, b_pub, 1.0f, nullptr, 0.f, rptr, out0, NP);
    k_mfma_rowgemm<<<(NP + 63) / 64, 256, 0, stream>>>(
        sumU, accEb, 4, 2, WpkC, b_com, 0.7f, b_ecom, 0.3f, rptr + NP, out1, NP);
}

// Round 7
// 425.079 us; speedup vs baseline: 17.7723x; 1.5198x over previous
//
#include <hip/hip_runtime.h>

typedef long long i64;
typedef unsigned int uint;
typedef unsigned long long u64;
typedef __attribute__((ext_vector_type(8))) short bf16x8;
typedef __attribute__((ext_vector_type(4))) float f32x4;

#define NU 100000
#define NP 100000
#define NSEG 300000   // pub dst' [0,NP), com [NP,2NP), ucu [2NP,2NP+NU)
#define LBKT 11
#define NBKT 160        // array sizing
#define NBKT_USED 147   // ceil(300000/2048)
#define FRONT_PRE 32
#define FRONT_CVT 18750 // NU*48/256

// ---------------- bf16 helpers ----------------
__device__ __forceinline__ uint f2b2(float x, float y) {
    uint ux = __float_as_uint(x), uy = __float_as_uint(y);
    ux = (ux + 0x7FFFu + ((ux >> 16) & 1u)) >> 16;
    uy = (uy + 0x7FFFu + ((uy >> 16) & 1u)) >> 16;
    return ux | (uy << 16);
}
__device__ __forceinline__ float blo(uint a) { return __uint_as_float(a << 16); }
__device__ __forceinline__ float bhi(uint a) { return __uint_as_float(a & 0xFFFF0000u); }

// ---------------- front: prepack | cvt | bucket-hist (fused, independent) ------
__global__ __launch_bounds__(256) void k_front(
    const float* __restrict__ W_pub, const float* __restrict__ W_com,
    const float* __restrict__ W_ecom, const float* __restrict__ W_conv,
    uint4* __restrict__ WpkP, uint4* __restrict__ WpkC, uint4* __restrict__ WpkZ,
    const float* __restrict__ hu, const float* __restrict__ ctx,
    uint* __restrict__ hu2, uint* __restrict__ ctx2,
    const int* __restrict__ pd, int n0, const int* __restrict__ cd, int n1,
    const int* __restrict__ ud, int n2, int* __restrict__ bcnt, int total)
{
    __shared__ int bh[NBKT];
    int bid = blockIdx.x;
    if (bid < FRONT_PRE) {
        // ---- weight prepack into MFMA B-fragment layout ----
        int gkt = bid >> 1;
        int sub = (bid & 1) * 256 + threadIdx.x;   // ct*64+lane
        int lane = sub & 63, ct = sub >> 6;
        int r = lane & 15, g = lane >> 4;
        const float* W; uint4* dst; int skt, dkt; float scale;
        if (gkt < 4)       { W = W_pub;              dst = WpkP; skt = gkt;      dkt = skt;     scale = 1.0f; }
        else if (gkt < 8)  { W = W_com;              dst = WpkC; skt = gkt - 4;  dkt = skt;     scale = 0.7f; }
        else if (gkt < 10) { W = W_ecom;             dst = WpkC; skt = gkt - 8;  dkt = skt + 4; scale = 0.3f; }
        else if (gkt < 14) { W = W_conv;             dst = WpkZ; skt = gkt - 10; dkt = skt;     scale = 1.0f; }
        else               { W = W_conv + 128 * 128; dst = WpkZ; skt = gkt - 14; dkt = skt + 4; scale = 1.0f; }
        float v[8];
#pragma unroll
        for (int jj = 0; jj < 8; ++jj)
            v[jj] = W[(i64)(skt * 32 + g * 8 + jj) * 128 + ct * 16 + r] * scale;
        uint4 o;
        o.x = f2b2(v[0], v[1]); o.y = f2b2(v[2], v[3]);
        o.z = f2b2(v[4], v[5]); o.w = f2b2(v[6], v[7]);
        dst[(dkt * 8 + ct) * 64 + lane] = o;
        return;
    }
    bid -= FRONT_PRE;
    if (bid < FRONT_CVT) {
        // ---- f32 -> bf16-pair conversion of h_user and user_ctx ----
        int t = bid * 256 + threadIdx.x;
        if (t < NU * 32) {
            float4 v = *(const float4*)(hu + (i64)t * 4);
            uint2 o; o.x = f2b2(v.x, v.y); o.y = f2b2(v.z, v.w);
            *(uint2*)(hu2 + (i64)t * 2) = o;
        } else {
            t -= NU * 32;
            float4 v = *(const float4*)(ctx + (i64)t * 4);
            uint2 o; o.x = f2b2(v.x, v.y); o.y = f2b2(v.z, v.w);
            *(uint2*)(ctx2 + (i64)t * 2) = o;
        }
        return;
    }
    bid -= FRONT_CVT;
    // ---- bucket-level histogram (160 counters) ----
    for (int i = threadIdx.x; i < NBKT; i += 256) bh[i] = 0;
    __syncthreads();
    int e0 = bid * 4096;
#pragma unroll
    for (int i = 0; i < 16; ++i) {
        int e = e0 + i * 256 + threadIdx.x;
        if (e < total) {
            int dp;
            if (e < n0) dp = pd[e];
            else if (e < n0 + n1) dp = NP + cd[e - n0];
            else dp = 2 * NP + ud[e - n0 - n1];
            atomicAdd(&bh[dp >> LBKT], 1);
        }
    }
    __syncthreads();
    for (int i = threadIdx.x; i < NBKT_USED; i += 256)
        if (bh[i]) atomicAdd(bcnt + i, bh[i]);
}

// ---------------- tiny scan: bucket counts -> bases + cursors ----------------
__global__ __launch_bounds__(256) void k_scanb(
    const int* __restrict__ bcnt, int* __restrict__ bbase,
    int* __restrict__ gcur, int* __restrict__ rptr)
{
    __shared__ int sm[256];
    int t = threadIdx.x;
    int v = (t < NBKT_USED) ? bcnt[t] : 0;
    sm[t] = v;
    __syncthreads();
    for (int off = 1; off < 256; off <<= 1) {
        int x = (t >= off) ? sm[t - off] : 0;
        __syncthreads();
        sm[t] += x;
        __syncthreads();
    }
    int excl = sm[t] - v;
    if (t < NBKT + 1 && t < 256) bbase[t] = excl;   // t>=147 -> total
    if (t < NBKT_USED) gcur[t] = excl;
    if (t == NBKT_USED) rptr[NSEG] = excl;          // total
}

// pass A: bucket records (src|dst'<<17|eid<<36) into 2048-dst buckets
#define TILE_A 4096
__global__ __launch_bounds__(256) void k_bucketA(
    const int* __restrict__ ps, const int* __restrict__ pd, int n0,
    const int* __restrict__ cs, const int* __restrict__ cd, int n1,
    const int* __restrict__ us, const int* __restrict__ ud, int n2,
    int* __restrict__ gcur, u64* __restrict__ recs, int total)
{
    __shared__ int hist[NBKT];
    __shared__ int base[NBKT];
    int t0 = blockIdx.x * TILE_A;
    for (int i = threadIdx.x; i < NBKT; i += 256) hist[i] = 0;
    __syncthreads();
    u64 rec[16];
    int bkt[16];
#pragma unroll
    for (int i = 0; i < 16; ++i) {
        int e = t0 + i * 256 + threadIdx.x;
        if (e < total) {
            int src, dp, eid;
            if (e < n0) { src = ps[e]; dp = pd[e]; eid = 0; }
            else if (e < n0 + n1) { int le = e - n0; src = cs[le]; dp = NP + cd[le]; eid = le; }
            else { int le = e - n0 - n1; src = us[le]; dp = 2 * NP + ud[le]; eid = 0; }
            rec[i] = (u64)src | ((u64)dp << 17) | ((u64)eid << 36);
            bkt[i] = dp >> LBKT;
            atomicAdd(&hist[bkt[i]], 1);
        } else bkt[i] = -1;
    }
    __syncthreads();
    for (int i = threadIdx.x; i < NBKT; i += 256) {
        int h = hist[i];
        base[i] = h ? atomicAdd(gcur + i, h) : 0;
    }
    __syncthreads();
    for (int i = threadIdx.x; i < NBKT; i += 256) hist[i] = 0;
    __syncthreads();
#pragma unroll
    for (int i = 0; i < 16; ++i) {
        if (bkt[i] >= 0) {
            int r = atomicAdd(&hist[bkt[i]], 1);
            recs[(i64)base[bkt[i]] + r] = rec[i];
        }
    }
}

// pass B: per-bucket LDS CSR build — writes rptr + ordered esrc4/rec8
__global__ __launch_bounds__(1024) void k_bucketB(
    const u64* __restrict__ recs, const int* __restrict__ bbase, int n0,
    int* __restrict__ rptr, int* __restrict__ esrc4, u64* __restrict__ rec8)
{
    __shared__ int h[2048];
    __shared__ int ss[1024];
    int b = blockIdx.x, tid = threadIdx.x;
    int bb = bbase[b], ne = bbase[b + 1] - bb;
    h[tid] = 0; h[tid + 1024] = 0;
    __syncthreads();
    for (int i = tid; i < ne; i += 1024)
        atomicAdd(&h[(int)((recs[bb + i] >> 17) & 2047)], 1);
    __syncthreads();
    int a0 = h[2 * tid], a1 = h[2 * tid + 1];
    int v = a0 + a1;
    ss[tid] = v;
    __syncthreads();
    for (int off = 1; off < 1024; off <<= 1) {
        int x = (tid >= off) ? ss[tid - off] : 0;
        __syncthreads();
        ss[tid] += x;
        __syncthreads();
    }
    int e0 = ss[tid] - v;       // exclusive over pairs
    int e1 = e0 + a0;
    h[2 * tid] = e0; h[2 * tid + 1] = e1;   // h becomes cursor
    // global rptr from registers (not h — h is being clobbered by pass2 atomics)
    int gbase = b * 2048;
    if (gbase + 2 * tid < NSEG)     rptr[gbase + 2 * tid]     = bb + e0;
    if (gbase + 2 * tid + 1 < NSEG) rptr[gbase + 2 * tid + 1] = bb + e1;
    __syncthreads();
    for (int i = tid; i < ne; i += 1024) {
        u64 rec = recs[bb + i];
        int ld = (int)((rec >> 17) & 2047);
        int dp = (int)((rec >> 17) & 0x7FFFF);
        int pos = bb + atomicAdd(&h[ld], 1);
        int src = (int)(rec & 0x1FFFF);
        if (dp >= NP && dp < 2 * NP)
            rec8[pos - n0] = (u64)(uint)src | ((rec >> 36) << 32);
        else
            esrc4[pos] = src;
    }
}

// ---------------- gather bodies (device) ----------------
__device__ __forceinline__ void gather128b_body(
    int row, const uint* __restrict__ feat, const int* __restrict__ rp,
    const int* __restrict__ esrc, int lane,
    float* __restrict__ outf, uint* __restrict__ outb, int divide)
{
    int beg = rp[row], end = rp[row + 1];
    float ax = 0.f, ay = 0.f;
    int j = beg;
    for (; j + 8 <= end; j += 8) {
        int s[8];
#pragma unroll
        for (int k = 0; k < 8; ++k) s[k] = esrc[j + k];
        uint a[8];
#pragma unroll
        for (int k = 0; k < 8; ++k) a[k] = feat[(i64)s[k] * 64 + lane];
#pragma unroll
        for (int k = 0; k < 8; ++k) { ax += blo(a[k]); ay += bhi(a[k]); }
    }
    if (j < end) {
        int rem = end - j;
        int s[8]; uint a[8];
#pragma unroll
        for (int k = 0; k < 8; ++k) s[k] = esrc[min(j + k, end - 1)];
#pragma unroll
        for (int k = 0; k < 8; ++k) a[k] = feat[(i64)s[k] * 64 + lane];
#pragma unroll
        for (int k = 0; k < 8; ++k) {
            float m = (k < rem) ? 1.f : 0.f;
            ax = fmaf(m, blo(a[k]), ax); ay = fmaf(m, bhi(a[k]), ay);
        }
    }
    if (outb) {
        outb[(i64)row * 64 + lane] = f2b2(ax, ay);
        return;
    }
    if (divide) {
        int deg = end - beg;
        float mm = deg > 0 ? 1.f / (float)deg : 0.f;
        ax *= mm; ay *= mm;
    }
    float2 o; o.x = ax; o.y = ay;
    *(float2*)(outf + (i64)row * 128 + lane * 2) = o;
}

__device__ __forceinline__ void gather_com_body(
    int row, const uint* __restrict__ hu2, const float* __restrict__ ec,
    const int* __restrict__ rp, const u64* __restrict__ rec8, int ebase, int lane,
    uint* __restrict__ outUb, uint* __restrict__ outEb)
{
    int beg = rp[row], end = rp[row + 1];
    float ax = 0.f, ay = 0.f, aE = 0.f;
    int j = beg;
    for (; j + 8 <= end; j += 8) {
        u64 r[8];
#pragma unroll
        for (int k = 0; k < 8; ++k) r[k] = rec8[j + k - ebase];
        uint a[8]; float f[8];
#pragma unroll
        for (int k = 0; k < 8; ++k) {
            int s = (int)(uint)r[k];
            int e = (int)(r[k] >> 32);
            a[k] = hu2[(i64)s * 64 + lane];
            f[k] = ec[(i64)e * 64 + lane];
        }
#pragma unroll
        for (int k = 0; k < 8; ++k) { ax += blo(a[k]); ay += bhi(a[k]); aE += f[k]; }
    }
    if (j < end) {
        int rem = end - j;
        u64 r[8];
#pragma unroll
        for (int k = 0; k < 8; ++k) r[k] = rec8[min(j + k, end - 1) - ebase];
        uint a[8]; float f[8];
#pragma unroll
        for (int k = 0; k < 8; ++k) {
            int s = (int)(uint)r[k];
            int e = (int)(r[k] >> 32);
            a[k] = hu2[(i64)s * 64 + lane];
            f[k] = ec[(i64)e * 64 + lane];
        }
#pragma unroll
        for (int k = 0; k < 8; ++k) {
            float m = (k < rem) ? 1.f : 0.f;
            ax = fmaf(m, blo(a[k]), ax); ay = fmaf(m, bhi(a[k]), ay);
            aE = fmaf(m, f[k], aE);
        }
    }
    outUb[(i64)row * 64 + lane] = f2b2(ax, ay);
    float aE2 = __shfl_xor(aE, 1);
    if (!(lane & 1)) outEb[(i64)row * 32 + (lane >> 1)] = f2b2(aE, aE2);
}

// fused: com | ucu | pub gathers
#define GG (NP * 64 / 256)
__global__ __launch_bounds__(256) void k_gathers3(
    const uint* __restrict__ hu2, const uint* __restrict__ zbuf,
    const float* __restrict__ ec, const int* __restrict__ rptr,
    const int* __restrict__ esrc4, const u64* __restrict__ rec8, int n_pub,
    float* __restrict__ out2, uint* __restrict__ sumP, uint* __restrict__ sumU,
    uint* __restrict__ accEb)
{
    int bid = blockIdx.x;
    int lane = threadIdx.x & 63;
    int wl = threadIdx.x >> 6;
    if (bid < GG) {
        gather_com_body(bid * 4 + wl, hu2, ec, rptr + NP, rec8, n_pub, lane, sumU, accEb);
    } else if (bid < 2 * GG) {
        gather128b_body((bid - GG) * 4 + wl, zbuf, rptr + 2 * NP, esrc4, lane, out2, nullptr, 1);
    } else {
        gather128b_body((bid - 2 * GG) * 4 + wl, hu2, rptr, esrc4, lane, nullptr, sumP, 0);
    }
}

// ---------------- MFMA z-GEMM (K=192) + fused LayerNorm + ReLU -> bf16 zbuf ------
__global__ __launch_bounds__(256) void k_mfma_zgemm_ln(
    const uint* __restrict__ hu2, const uint* __restrict__ ctx2,
    const uint4* __restrict__ Wp, const float* __restrict__ bias,
    const float* __restrict__ ln_g, const float* __restrict__ ln_b,
    uint* __restrict__ zout)
{
    const int wave = threadIdx.x >> 6;
    const int lane = threadIdx.x & 63;
    const int row0 = blockIdx.x * 64 + wave * 16;
    const int r = lane & 15, g = lane >> 4;
    const int arow = min(row0 + r, NU - 1);
    const bf16x8* wp = (const bf16x8*)Wp;

    f32x4 acc[8];
#pragma unroll
    for (int ct = 0; ct < 8; ++ct) acc[ct] = (f32x4){0.f, 0.f, 0.f, 0.f};

    const uint* xu = hu2 + (i64)arow * 64 + g * 4;
#pragma unroll
    for (int kt = 0; kt < 4; ++kt) {
        bf16x8 a = *(const bf16x8*)(xu + kt * 16);
#pragma unroll
        for (int ct = 0; ct < 8; ++ct)
            acc[ct] = __builtin_amdgcn_mfma_f32_16x16x32_bf16(
                a, wp[(kt * 8 + ct) * 64 + lane], acc[ct], 0, 0, 0);
    }
    const uint* xe = ctx2 + (i64)arow * 32 + g * 4;
#pragma unroll
    for (int kt = 0; kt < 2; ++kt) {
        bf16x8 a = *(const bf16x8*)(xe + kt * 16);
#pragma unroll
        for (int ct = 0; ct < 8; ++ct)
            acc[ct] = __builtin_amdgcn_mfma_f32_16x16x32_bf16(
                a, wp[((4 + kt) * 8 + ct) * 64 + lane], acc[ct], 0, 0, 0);
    }

    float bv[8], gv[8], bbv[8];
#pragma unroll
    for (int ct = 0; ct < 8; ++ct) {
        bv[ct] = bias[ct * 16 + r];
        gv[ct] = ln_g[ct * 16 + r];
        bbv[ct] = ln_b[ct * 16 + r];
    }

#pragma unroll
    for (int q = 0; q < 4; ++q) {
        int orow = row0 + g * 4 + q;
        float v[8], s = 0.f;
#pragma unroll
        for (int ct = 0; ct < 8; ++ct) { v[ct] = acc[ct][q] + bv[ct]; s += v[ct]; }
#pragma unroll
        for (int m = 1; m < 16; m <<= 1) s += __shfl_xor(s, m);
        float mu = s * (1.f / 128.f);
        float sq = 0.f;
#pragma unroll
        for (int ct = 0; ct < 8; ++ct) { float d = v[ct] - mu; sq += d * d; }
#pragma unroll
        for (int m = 1; m < 16; m <<= 1) sq += __shfl_xor(sq, m);
        float rs = rsqrtf(sq * (1.f / 128.f) + 1e-5f);
        float o[8];
#pragma unroll
        for (int ct = 0; ct < 8; ++ct)
            o[ct] = fmaxf(0.f, (v[ct] - mu) * rs * gv[ct] + bbv[ct]);
#pragma unroll
        for (int ct = 0; ct < 8; ++ct) {
            float p = __shfl_xor(o[ct], 1);
            if (!(r & 1) && orow < NU)
                zout[(i64)orow * 64 + ct * 8 + (r >> 1)] = f2b2(o[ct], p);
        }
    }
}

// ---------------- MFMA rowwise GEMM body ----------------
__device__ __forceinline__ void rowgemm_body(
    int bid, int tid, const uint* __restrict__ Xu, const uint* __restrict__ Xe,
    int nktU, int nktE, const uint4* __restrict__ Wp,
    const float* __restrict__ b0, float bs0,
    const float* __restrict__ b1, float bs1,
    const int* __restrict__ rp, float* __restrict__ out, int nrow)
{
    const int wave = tid >> 6;
    const int lane = tid & 63;
    const int row0 = bid * 64 + wave * 16;
    const int r = lane & 15, g = lane >> 4;
    const int arow = min(row0 + r, nrow - 1);
    const bf16x8* wp = (const bf16x8*)Wp;

    f32x4 acc[8];
#pragma unroll
    for (int ct = 0; ct < 8; ++ct) acc[ct] = (f32x4){0.f, 0.f, 0.f, 0.f};

    const int ldu = nktU * 16;
    const uint* xu = Xu + (i64)arow * ldu + g * 4;
    for (int kt = 0; kt < nktU; ++kt) {
        bf16x8 a = *(const bf16x8*)(xu + kt * 16);
#pragma unroll
        for (int ct = 0; ct < 8; ++ct)
            acc[ct] = __builtin_amdgcn_mfma_f32_16x16x32_bf16(
                a, wp[(kt * 8 + ct) * 64 + lane], acc[ct], 0, 0, 0);
    }
    if (nktE) {
        const int lde = nktE * 16;
        const uint* xe = Xe + (i64)arow * lde + g * 4;
        for (int kt = 0; kt < nktE; ++kt) {
            bf16x8 a = *(const bf16x8*)(xe + kt * 16);
#pragma unroll
            for (int ct = 0; ct < 8; ++ct)
                acc[ct] = __builtin_amdgcn_mfma_f32_16x16x32_bf16(
                    a, wp[((nktU + kt) * 8 + ct) * 64 + lane], acc[ct], 0, 0, 0);
        }
    }

    float bv[8];
#pragma unroll
    for (int ct = 0; ct < 8; ++ct) {
        float b = bs0 * b0[ct * 16 + r];
        if (b1) b += bs1 * b1[ct * 16 + r];
        bv[ct] = b;
    }

#pragma unroll
    for (int q = 0; q < 4; ++q) {
        int orow = row0 + g * 4 + q;
        if (orow < nrow) {
            int deg = rp[orow + 1] - rp[orow];
            float m = deg > 0 ? 1.f / (float)deg : 0.f;
            float gate = deg > 0 ? 1.f : 0.f;
#pragma unroll
            for (int ct = 0; ct < 8; ++ct)
                out[(i64)orow * 128 + ct * 16 + r] = gate * fmaf(acc[ct][q], m, bv[ct]);
        }
    }
}

#define GB ((NP + 63) / 64)
__global__ __launch_bounds__(256) void k_rowgemms2(
    const uint* __restrict__ sumP, const uint* __restrict__ sumU,
    const uint* __restrict__ accEb, const uint4* __restrict__ WpkP,
    const uint4* __restrict__ WpkC, const float* __restrict__ b_pub,
    const float* __restrict__ b_com, const float* __restrict__ b_ecom,
    const int* __restrict__ rptr, float* __restrict__ out0, float* __restrict__ out1)
{
    int bid = blockIdx.x;
    if (bid < GB)
        rowgemm_body(bid, threadIdx.x, sumP, nullptr, 4, 0, WpkP,
                     b_pub, 1.0f, nullptr, 0.f, rptr, out0, NP);
    else
        rowgemm_body(bid - GB, threadIdx.x, sumU, accEb, 4, 2, WpkC,
                     b_com, 0.7f, b_ecom, 0.3f, rptr + NP, out1, NP);
}

extern "C" void kernel_launch(void* const* d_in, const int* in_sizes, int n_in,
                              void* d_out, int out_size, void* d_ws, size_t ws_size,
                              hipStream_t stream)
{
    const float* h_user   = (const float*)d_in[0];
    const float* user_ctx = (const float*)d_in[2];
    const float* e_com    = (const float*)d_in[3];
    const int* pub_src = (const int*)d_in[4];
    const int* pub_dst = (const int*)d_in[5];
    const int* com_src = (const int*)d_in[6];
    const int* com_dst = (const int*)d_in[7];
    const int* ucu_src = (const int*)d_in[8];
    const int* ucu_dst = (const int*)d_in[9];
    const float* W_pub  = (const float*)d_in[10];
    const float* b_pub  = (const float*)d_in[11];
    const float* W_com  = (const float*)d_in[12];
    const float* b_com  = (const float*)d_in[13];
    const float* W_conv = (const float*)d_in[14];
    const float* b_conv = (const float*)d_in[15];
    const float* ln_g   = (const float*)d_in[16];
    const float* ln_b   = (const float*)d_in[17];
    const float* W_ecom = (const float*)d_in[18];
    const float* b_ecom = (const float*)d_in[19];

    const int n_pub = in_sizes[4];
    const int n_com = in_sizes[6];
    const int n_ucu = in_sizes[8];
    const int total = n_pub + n_com + n_ucu;

    float* out0 = (float*)d_out;
    float* out1 = out0 + (i64)NP * 128;
    float* out2 = out1 + (i64)NP * 128;

    // ---- ws layout; zbuf overlays recsA (recsA dead after bucketB) ----
    char* ws = (char*)d_ws;
    i64 off = 0;
    auto alloc = [&](i64 bytes) { i64 p = off; off += (bytes + 15) & ~15LL; return p; };
    uint* hu2   = (uint*)(ws + alloc((i64)NU * 64 * 4));
    uint* ctx2  = (uint*)(ws + alloc((i64)NU * 32 * 4));
    i64 reg2_sz = (i64)total * 8 > (i64)NU * 64 * 4 ? (i64)total * 8 : (i64)NU * 64 * 4;
    i64 reg2    = alloc(reg2_sz);
    u64* recsA  = (u64*)(ws + reg2);
    uint* zbuf  = (uint*)(ws + reg2);
    uint* sumP  = (uint*)(ws + alloc((i64)NP * 64 * 4));
    uint* sumU  = (uint*)(ws + alloc((i64)NP * 64 * 4));
    uint* accEb = (uint*)(ws + alloc((i64)NP * 32 * 4));
    u64* rec8   = (u64*)(ws + alloc((i64)n_com * 8));
    int* rptr   = (int*)(ws + alloc((i64)(NSEG + 1) * 4));
    int* bcnt   = (int*)(ws + alloc(NBKT * 4));
    int* bbase  = (int*)(ws + alloc((NBKT + 1) * 4));
    int* gcur   = (int*)(ws + alloc(NBKT * 4));
    int* esrc4  = (int*)(ws + alloc((i64)total * 4));
    uint4* WpkP = (uint4*)(ws + alloc(4 * 8 * 64 * 16));   // W_pub, K=128
    uint4* WpkC = (uint4*)(ws + alloc(6 * 8 * 64 * 16));   // [0.7*W_com ; 0.3*W_ecom], K=192
    uint4* WpkZ = (uint4*)(ws + alloc(6 * 8 * 64 * 16));   // W_conv, K=192

    const int nbh = (total + 4095) / 4096;

    // 1. front: prepack | bf16 cvt | bucket hist
    hipMemsetAsync(bcnt, 0, NBKT * 4, stream);
    k_front<<<FRONT_PRE + FRONT_CVT + nbh, 256, 0, stream>>>(
        W_pub, W_com, W_ecom, W_conv, WpkP, WpkC, WpkZ,
        h_user, user_ctx, hu2, ctx2,
        pub_dst, n_pub, com_dst, n_com, ucu_dst, n_ucu, bcnt, total);

    // 2. bucket bases
    k_scanb<<<1, 256, 0, stream>>>(bcnt, bbase, gcur, rptr);

    // 3. bucket scatter of packed records
    k_bucketA<<<(total + TILE_A - 1) / TILE_A, 256, 0, stream>>>(
        pub_src, pub_dst, n_pub, com_src, com_dst, n_com,
        ucu_src, ucu_dst, n_ucu, gcur, recsA, total);

    // 4. per-bucket LDS CSR build -> rptr + esrc4/rec8
    k_bucketB<<<NBKT_USED, 1024, 0, stream>>>(
        recsA, bbase, n_pub, rptr, esrc4, rec8);

    // 5. z = relu(LN(concat(hu,ctx) @ W_conv + b)) via MFMA -> bf16 zbuf
    k_mfma_zgemm_ln<<<(NU + 63) / 64, 256, 0, stream>>>(
        hu2, ctx2, WpkZ, b_conv, ln_g, ln_b, zbuf);

    // 6. fused gathers: com | ucu | pub
    k_gathers3<<<3 * GG, 256, 0, stream>>>(
        hu2, zbuf, e_com, rptr, esrc4, rec8, n_pub, out2, sumP, sumU, accEb);

    // 7. fused relation GEMMs
    k_rowgemms2<<<2 * GB, 256, 0, stream>>>(
        sumP, sumU, accEb, WpkP, WpkC, b_pub, b_com, b_ecom, rptr, out0, out1);
}